// Round 5
// baseline (259.504 us; speedup 1.0000x reference)
//
#include <hip/hip_runtime.h>
#include <math.h>

#define BB 32768
#define DD 512
#define CC 527
#define NCOLP 576   // padded W cols in Wbf (layout unchanged; only 33 tiles read)
#define BM 32       // rows per block
#define ZSH 552     // LDS z row stride (u16): 1104 B = 16B-aligned; quads spread 2 bank-groups
#define XST 520     // LDS x row stride (bf16)

typedef __attribute__((ext_vector_type(8))) short bf16x8;
typedef __attribute__((ext_vector_type(4))) short bf16x4;
typedef __attribute__((ext_vector_type(4))) float f32x4;
typedef __attribute__((ext_vector_type(4))) unsigned int u32x4;
typedef f32x4 f32x4u __attribute__((aligned(4)));   // y rows only 4B-aligned (527 odd)

#define TJ4(OP) OP(0) OP(1) OP(2) OP(3)
#define C4(OP)  OP(0) OP(1) OP(2) OP(3)

#if __has_builtin(__builtin_amdgcn_exp2f)
#define EXP2F(v) __builtin_amdgcn_exp2f(v)
#else
#define EXP2F(v) exp2f(v)
#endif
#if __has_builtin(__builtin_amdgcn_logf)
#define LOG2F(v) __builtin_amdgcn_logf(v)
#else
#define LOG2F(v) __log2f(v)
#endif

__device__ __forceinline__ short f2bf(float f) {  // fp32 -> bf16 RNE
  unsigned u = __float_as_uint(f);
  u += 0x7fffu + ((u >> 16) & 1u);
  return (short)(u >> 16);
}
__device__ __forceinline__ bf16x8 pack8(f32x4 a, f32x4 b) {
  bf16x8 v;
  v[0]=f2bf(a.x); v[1]=f2bf(a.y); v[2]=f2bf(a.z); v[3]=f2bf(a.w);
  v[4]=f2bf(b.x); v[5]=f2bf(b.y); v[6]=f2bf(b.z); v[7]=f2bf(b.w);
  return v;
}

// 16-lane (DPP row) reductions: 4 x row_ror, pure VALU, no LDS pipe.
__device__ __forceinline__ int dppadd16(int v) {
  v += __builtin_amdgcn_update_dpp(0, v, 0x121, 0xf, 0xf, false);
  v += __builtin_amdgcn_update_dpp(0, v, 0x122, 0xf, 0xf, false);
  v += __builtin_amdgcn_update_dpp(0, v, 0x124, 0xf, 0xf, false);
  v += __builtin_amdgcn_update_dpp(0, v, 0x128, 0xf, 0xf, false);
  return v;
}
__device__ __forceinline__ int dppmax16i(int v) {
  int t;
  t = __builtin_amdgcn_update_dpp(0, v, 0x121, 0xf, 0xf, false); v = v > t ? v : t;
  t = __builtin_amdgcn_update_dpp(0, v, 0x122, 0xf, 0xf, false); v = v > t ? v : t;
  t = __builtin_amdgcn_update_dpp(0, v, 0x124, 0xf, 0xf, false); v = v > t ? v : t;
  t = __builtin_amdgcn_update_dpp(0, v, 0x128, 0xf, 0xf, false); v = v > t ? v : t;
  return v;
}

// bf16 bits -> order-preserving u16, then (mono<<10)|col: strict total order,
// no ties -> integer bisection always terminates on exact count match.
#define KEYOF(b, idx) ((int)(((((unsigned)(b)) ^ (0x8000u | (0xFFFFu * (((unsigned)(b)) >> 15)))) << 10) | (unsigned)(idx)))

// Block = 512 thr = 8 waves, 4 blocks/CU (LDS 35.4 KB, VGPR <= 64). Prologue:
// x tile -> LDS bf16. GEMM: wave = 2 rowsets x 4-5 col-tiles (33 tiles cover
// C=527); B addressed via readfirstlane SGPR bases + one shared VGPR offset
// (no per-tile VGPR pointers); A via one LDS base + imm offsets. z -> LDS bf16.
// Epilogue is TWO passes to cap pressure (round-4 spilled at 33 keys + y regs):
// pass 1 streams z/y/pw for loss+masks; pass 2 re-reads z, builds 33 int keys,
// exact tie-free integer bisection with DPP-only reductions.
template<bool PRE>
__global__ __launch_bounds__(512, 8)
void fused_mfma_bce_topk(const float* __restrict__ x, const float* __restrict__ y,
                         const float* __restrict__ W, const short* __restrict__ Wbf,
                         const float* __restrict__ bias, const float* __restrict__ pw,
                         float* __restrict__ accum) {
  __shared__ __attribute__((aligned(16))) unsigned short zs_h[BM][ZSH]; // 35,328 B
  __shared__ float redL[8], redS[8];

  const int tid  = threadIdx.x;
  const int w    = tid >> 6, lane = tid & 63;
  const int cl   = lane & 15, quad = lane >> 4;
  const int row0 = blockIdx.x * BM;

  // ---------------- x -> LDS as bf16 (coalesced) ----------------
  unsigned short* xs = &zs_h[0][0];   // [BM][XST] bf16 stage, 33,280 B (unions)
  {
    const float* xblk = x + (size_t)row0 * DD;
#pragma unroll
    for (int i = 0; i < 8; ++i) {
      const int e = i * 2048 + tid * 4;        // f32 element index in 32x512 tile
      f32x4 v = *(const f32x4*)(xblk + e);
      const int r = e >> 9, c = e & 511;
      bf16x4 bv;
      bv[0] = f2bf(v.x); bv[1] = f2bf(v.y); bv[2] = f2bf(v.z); bv[3] = f2bf(v.w);
      *(bf16x4*)(xs + r * XST + c) = bv;       // ds_write_b64
    }
  }
  __syncthreads();

  // tile ranges: wave 0 -> [0,5), wave w>=1 -> [4w+1, 4w+5); 33 tiles total
  const int t0  = (w == 0) ? 0 : 4 * w + 1;
  const bool nt5 = (w == 0);
  const int t0u = __builtin_amdgcn_readfirstlane(t0);   // force SGPR (wave-uniform)

#define DECL(j) f32x4 P##j = (f32x4){0.f,0.f,0.f,0.f}; f32x4 Q##j = (f32x4){0.f,0.f,0.f,0.f};
  TJ4(DECL) DECL(4)
#undef DECL

  // ---------------- MFMA GEMM over K = 512 (A from LDS) ----------------
  const unsigned short* xr = xs + (size_t)cl * XST + quad * 8;   // rowset 1 = +16*XST (imm)

  if (PRE) {
    const short* wb = Wbf + (size_t)t0u * (16 * DD);   // SGPR base
    const int voff = cl * DD + quad * 8;               // shared VGPR offset (elems)
#define GSTEP(j) { \
    bf16x8 bfr = *(const bf16x8*)(wb + (j) * (16 * DD) + voff + k0); \
    P##j = __builtin_amdgcn_mfma_f32_16x16x32_bf16(a0, bfr, P##j, 0, 0, 0); \
    Q##j = __builtin_amdgcn_mfma_f32_16x16x32_bf16(a1, bfr, Q##j, 0, 0, 0); }
    for (int k0 = 0; k0 < DD; k0 += 32) {
      bf16x8 a0 = *(const bf16x8*)(xr + k0);
      bf16x8 a1 = *(const bf16x8*)(xr + 16 * XST + k0);
      TJ4(GSTEP)
      if (nt5) { GSTEP(4) }
    }
#undef GSTEP
  } else {
#define GSTEPF(j) { \
    int col = (t0 + (j)) * 16 + cl; \
    bf16x8 bfr = {0,0,0,0,0,0,0,0}; \
    if (col < CC) { \
      const float* wp = W + (size_t)col * DD + k0 + quad * 8; \
      bfr = pack8(*(const f32x4*)wp, *(const f32x4*)(wp + 4)); \
    } \
    P##j = __builtin_amdgcn_mfma_f32_16x16x32_bf16(a0, bfr, P##j, 0, 0, 0); \
    Q##j = __builtin_amdgcn_mfma_f32_16x16x32_bf16(a1, bfr, Q##j, 0, 0, 0); }
    for (int k0 = 0; k0 < DD; k0 += 32) {
      bf16x8 a0 = *(const bf16x8*)(xr + k0);
      bf16x8 a1 = *(const bf16x8*)(xr + 16 * XST + k0);
      TJ4(GSTEPF)
      if (nt5) { GSTEPF(4) }
    }
#undef GSTEPF
  }

  // bias per owned tile (transient; overlaps the pre-z-write barrier drain)
#define LB(j) float bt##j = 0.f; { int col = (t0 + (j)) * 16 + cl; if (col < CC) bt##j = bias[col]; }
  TJ4(LB)
  float bt4 = 0.f;
  if (nt5) { bt4 = bias[4 * 16 + cl]; }
#undef LB

  // all A-reads done before zs_h overwrites the x-stage region
  __syncthreads();

  // ---------------- z (+bias) -> LDS as bf16 ----------------
  // C/D layout: col = (t0+j)*16 + cl (<= 527 < ZSH), rows quad*4+r / 16+quad*4+r
#define WRZ(j) { \
    const int col = (t0 + (j)) * 16 + cl; \
    const int rr0 = quad * 4; \
    zs_h[rr0 + 0][col] = (unsigned short)f2bf(P##j[0] + bt##j); \
    zs_h[rr0 + 1][col] = (unsigned short)f2bf(P##j[1] + bt##j); \
    zs_h[rr0 + 2][col] = (unsigned short)f2bf(P##j[2] + bt##j); \
    zs_h[rr0 + 3][col] = (unsigned short)f2bf(P##j[3] + bt##j); \
    zs_h[16 + rr0 + 0][col] = (unsigned short)f2bf(Q##j[0] + bt##j); \
    zs_h[16 + rr0 + 1][col] = (unsigned short)f2bf(Q##j[1] + bt##j); \
    zs_h[16 + rr0 + 2][col] = (unsigned short)f2bf(Q##j[2] + bt##j); \
    zs_h[16 + rr0 + 3][col] = (unsigned short)f2bf(Q##j[3] + bt##j); }
  TJ4(WRZ)
  if (nt5) { WRZ(4) }
#undef WRZ

  __syncthreads();

  // ---------------- epilogue: one row per 16-lane group ----------------
  // group (w,quad) owns row erow; lane cl owns cols {128t+8cl..+7, t<4} + tail 512+cl
  const int erow = w * 4 + quad;                 // 0..31
  const float* yrow = y + (size_t)(row0 + erow) * CC;

  // ---- pass 1: loss + positive masks (streaming, low register footprint) ----
  unsigned ym0 = 0, ym1 = 0;
  float lossloc = 0.f;
#define LE(t, e) { \
    unsigned b = (((e) & 1) ? (zr[(e) >> 1] >> 16) : (zr[(e) >> 1] & 0xFFFFu)); \
    float z = __uint_as_float(b << 16); \
    float yv = ((e) < 4) ? ya[(e)] : yb[(e) - 4]; \
    float pv = ((e) < 4) ? pa[(e)] : pb[(e) - 4]; \
    float l1 = LOG2F(1.f + EXP2F(fabsf(z) * -1.4426950408889634f)) * 0.6931471805599453f; \
    float sp = fmaxf(z, 0.f) + l1; \
    lossloc += pv * yv * (sp - z) + (1.f - yv) * sp; \
    if (yv > 0.5f) ym0 |= (1u << (8*(t)+(e))); }
#define LCH(t) { \
    u32x4 zr = *(const u32x4*)&zs_h[erow][128*(t) + 8*cl]; \
    f32x4 ya = (f32x4)(*(const f32x4u*)(yrow + 128*(t) + 8*cl)); \
    f32x4 yb = (f32x4)(*(const f32x4u*)(yrow + 128*(t) + 8*cl + 4)); \
    f32x4 pa = *(const f32x4*)(pw + 128*(t) + 8*cl); \
    f32x4 pb = *(const f32x4*)(pw + 128*(t) + 8*cl + 4); \
    LE(t,0) LE(t,1) LE(t,2) LE(t,3) LE(t,4) LE(t,5) LE(t,6) LE(t,7) }
  C4(LCH)
#undef LCH
#undef LE
  if (cl < 15) {              // tail cols 512..526
    const int col = 512 + cl;
    unsigned b = zs_h[erow][col];
    float z = __uint_as_float(b << 16);
    float yv = yrow[col];
    float pv = pw[col];
    float l1 = LOG2F(1.f + EXP2F(fabsf(z) * -1.4426950408889634f)) * 0.6931471805599453f;
    float sp = fmaxf(z, 0.f) + l1;
    lossloc += pv * yv * (sp - z) + (1.f - yv) * sp;
    if (yv > 0.5f) ym1 = 1u;
  }

  const int kk = dppadd16(__popc(ym0) + (int)ym1);

  // ---- pass 2: keys from LDS (z still resident), then integer bisection ----
#define KDECL(t) int K##t##_0, K##t##_1, K##t##_2, K##t##_3, K##t##_4, K##t##_5, K##t##_6, K##t##_7;
  C4(KDECL)
#undef KDECL
  int K32 = 0;
#define KE(t, e) { \
    unsigned b = (((e) & 1) ? (zr[(e) >> 1] >> 16) : (zr[(e) >> 1] & 0xFFFFu)); \
    K##t##_##e = KEYOF(b, 128*(t) + 8*cl + (e)); }
#define KCH(t) { \
    u32x4 zr = *(const u32x4*)&zs_h[erow][128*(t) + 8*cl]; \
    KE(t,0) KE(t,1) KE(t,2) KE(t,3) KE(t,4) KE(t,5) KE(t,6) KE(t,7) }
  C4(KCH)
#undef KCH
#undef KE
  if (cl < 15) {
    unsigned b = zs_h[erow][512 + cl];
    K32 = KEYOF(b, 512 + cl);
  }

  // bracket: [-1, max-key]; integer bisection, exact count match guaranteed
  int mxK = K32;
#define MXK(t) { int m01 = K##t##_0 > K##t##_1 ? K##t##_0 : K##t##_1; \
    int m23 = K##t##_2 > K##t##_3 ? K##t##_2 : K##t##_3; \
    int m45 = K##t##_4 > K##t##_5 ? K##t##_4 : K##t##_5; \
    int m67 = K##t##_6 > K##t##_7 ? K##t##_6 : K##t##_7; \
    int ma = m01 > m23 ? m01 : m23; int mb = m45 > m67 ? m45 : m67; \
    int mc = ma > mb ? ma : mb; mxK = mxK > mc ? mxK : mc; }
  C4(MXK)
#undef MXK
  mxK = dppmax16i(mxK);

  int lo = -1, hi = mxK, th = 0;
  bool fnd = false;
#pragma unroll 1
  for (int it = 0; it < 32; ++it) {
    const int tm = (lo + hi) >> 1;
    int c = (K32 > tm);
#define CK(t) c += (K##t##_0 > tm) + (K##t##_1 > tm) + (K##t##_2 > tm) + (K##t##_3 > tm) \
             + (K##t##_4 > tm) + (K##t##_5 > tm) + (K##t##_6 > tm) + (K##t##_7 > tm);
    C4(CK)
#undef CK
    c = dppadd16(c);
    if (!fnd) {
      if (c == kk)                   { th = tm; fnd = true; }
      else if (tm <= lo || tm >= hi) { th = lo; fnd = true; }
      else if (c > kk)               lo = tm;
      else                           hi = tm;
    }
    if (__all(fnd)) break;
  }
  if (!fnd) th = lo;

  // hits among positives: decision = key > th
  int h = (int)(ym1 & (unsigned)(K32 > th));
#define HT(t) h += (int)((ym0 >> (8*(t)+0)) & 1u) & (int)(K##t##_0 > th); \
  h += (int)((ym0 >> (8*(t)+1)) & 1u) & (int)(K##t##_1 > th); \
  h += (int)((ym0 >> (8*(t)+2)) & 1u) & (int)(K##t##_2 > th); \
  h += (int)((ym0 >> (8*(t)+3)) & 1u) & (int)(K##t##_3 > th); \
  h += (int)((ym0 >> (8*(t)+4)) & 1u) & (int)(K##t##_4 > th); \
  h += (int)((ym0 >> (8*(t)+5)) & 1u) & (int)(K##t##_5 > th); \
  h += (int)((ym0 >> (8*(t)+6)) & 1u) & (int)(K##t##_6 > th); \
  h += (int)((ym0 >> (8*(t)+7)) & 1u) & (int)(K##t##_7 > th);
  C4(HT)
#undef HT
  h = dppadd16(h);

  float scoreloc = 0.f;
  if (cl == 0) {
    const int hv = h < kk ? h : kk;   // safety clamp
    scoreloc = (float)hv / (float)kk;
  }

  // loss+score: wave butterfly; block: LDS + one atomic per block per output
#pragma unroll
  for (int m = 1; m < 64; m <<= 1) {
    lossloc  += __shfl_xor(lossloc, m, 64);
    scoreloc += __shfl_xor(scoreloc, m, 64);
  }
  if (lane == 0) { redL[w] = lossloc; redS[w] = scoreloc; }
  __syncthreads();
  if (tid == 0) {
    float sl = 0.f, ss = 0.f;
#pragma unroll
    for (int i = 0; i < 8; ++i) { sl += redL[i]; ss += redS[i]; }
    atomicAdd(&accum[0], sl);
    atomicAdd(&accum[1], ss);
  }
}

__global__ void wcvt_kernel(const float* __restrict__ W, short* __restrict__ Wbf,
                            float* __restrict__ ws) {
  if (blockIdx.x == 0 && threadIdx.x == 0) { ws[0] = 0.f; ws[1] = 0.f; }
  int idx = (blockIdx.x * 256 + threadIdx.x) * 4;   // elem in [576*512]
  int row = idx >> 9;
  bf16x4 v = {0, 0, 0, 0};
  if (row < CC) {
    f32x4 f = *(const f32x4*)(W + idx);
    v[0]=f2bf(f.x); v[1]=f2bf(f.y); v[2]=f2bf(f.z); v[3]=f2bf(f.w);
  }
  *(bf16x4*)(Wbf + idx) = v;
}

__global__ void init_ws_kernel(float* ws) {
  ws[0] = 0.f;
  ws[1] = 0.f;
}

__global__ void finalize_kernel(const float* __restrict__ ws, float* __restrict__ out) {
  out[0] = (float)((double)ws[0] / ((double)BB * (double)CC));
  out[1] = (float)((double)ws[1] / (double)BB);
}

extern "C" void kernel_launch(void* const* d_in, const int* in_sizes, int n_in,
                              void* d_out, int out_size, void* d_ws, size_t ws_size,
                              hipStream_t stream) {
  const float* x  = (const float*)d_in[0];
  const float* y  = (const float*)d_in[1];
  const float* W  = (const float*)d_in[2];
  const float* b  = (const float*)d_in[3];
  const float* pw = (const float*)d_in[4];
  float* out = (float*)d_out;
  float* ws  = (float*)d_ws;
  short* Wbf = (short*)((char*)d_ws + 64);

  const size_t need = 64 + (size_t)NCOLP * DD * 2;
  const bool pre = (ws_size >= need);

  if (pre) {
    wcvt_kernel<<<dim3(NCOLP * DD / 1024), dim3(256), 0, stream>>>(W, Wbf, ws);
    fused_mfma_bce_topk<true><<<dim3(BB / BM), dim3(512), 0, stream>>>(
        x, y, W, Wbf, b, pw, ws);
  } else {
    init_ws_kernel<<<dim3(1), dim3(1), 0, stream>>>(ws);
    fused_mfma_bce_topk<false><<<dim3(BB / BM), dim3(512), 0, stream>>>(
        x, y, W, Wbf, b, pw, ws);
  }
  finalize_kernel<<<dim3(1), dim3(1), 0, stream>>>(ws, out);
}

// Round 6
// 254.367 us; speedup vs baseline: 1.0202x; 1.0202x over previous
//
#include <hip/hip_runtime.h>
#include <math.h>

#define BB 32768
#define DD 512
#define CC 527
#define NCOLP 576   // padded W cols in Wbf (layout unchanged; only 33 tiles read)
#define BM 32       // rows per block
#define ZSH 552     // LDS z row stride (u16): 1104 B, 16B-aligned; 2 bank-groups
#define XST 520     // LDS x row stride (bf16)

typedef __attribute__((ext_vector_type(8))) short bf16x8;
typedef __attribute__((ext_vector_type(4))) short bf16x4;
typedef __attribute__((ext_vector_type(4))) float f32x4;
typedef __attribute__((ext_vector_type(4))) unsigned int u32x4;
typedef f32x4 f32x4u __attribute__((aligned(4)));   // y rows only 4B-aligned (527 odd)

#define TJ4(OP) OP(0) OP(1) OP(2) OP(3)
#define C4(OP)  OP(0) OP(1) OP(2) OP(3)

#if __has_builtin(__builtin_amdgcn_exp2f)
#define EXP2F(v) __builtin_amdgcn_exp2f(v)
#else
#define EXP2F(v) exp2f(v)
#endif
#if __has_builtin(__builtin_amdgcn_logf)
#define LOG2F(v) __builtin_amdgcn_logf(v)
#else
#define LOG2F(v) __log2f(v)
#endif

__device__ __forceinline__ short f2bf(float f) {  // fp32 -> bf16 RNE
  unsigned u = __float_as_uint(f);
  u += 0x7fffu + ((u >> 16) & 1u);
  return (short)(u >> 16);
}
__device__ __forceinline__ bf16x8 pack8(f32x4 a, f32x4 b) {
  bf16x8 v;
  v[0]=f2bf(a.x); v[1]=f2bf(a.y); v[2]=f2bf(a.z); v[3]=f2bf(a.w);
  v[4]=f2bf(b.x); v[5]=f2bf(b.y); v[6]=f2bf(b.z); v[7]=f2bf(b.w);
  return v;
}

// 16-lane (DPP row) reductions: 4 x row_ror, pure VALU, no LDS pipe.
__device__ __forceinline__ int dppadd16(int v) {
  v += __builtin_amdgcn_update_dpp(0, v, 0x121, 0xf, 0xf, false);
  v += __builtin_amdgcn_update_dpp(0, v, 0x122, 0xf, 0xf, false);
  v += __builtin_amdgcn_update_dpp(0, v, 0x124, 0xf, 0xf, false);
  v += __builtin_amdgcn_update_dpp(0, v, 0x128, 0xf, 0xf, false);
  return v;
}
__device__ __forceinline__ int dppmax16i(int v) {
  int t;
  t = __builtin_amdgcn_update_dpp(0, v, 0x121, 0xf, 0xf, false); v = v > t ? v : t;
  t = __builtin_amdgcn_update_dpp(0, v, 0x122, 0xf, 0xf, false); v = v > t ? v : t;
  t = __builtin_amdgcn_update_dpp(0, v, 0x124, 0xf, 0xf, false); v = v > t ? v : t;
  t = __builtin_amdgcn_update_dpp(0, v, 0x128, 0xf, 0xf, false); v = v > t ? v : t;
  return v;
}

// bf16 bits -> order-preserving u16, then (mono<<10)|col: strict total order,
// no ties -> integer bisection always terminates on exact count match.
#define KEYOF(b, idx) ((int)(((((unsigned)(b)) ^ (0x8000u | (0xFFFFu * (((unsigned)(b)) >> 15)))) << 10) | (unsigned)(idx)))

// Block = 512 thr = 8 waves. launch_bounds(512,6): 84-reg unified budget ->
// GEMM (40 acc + frags + ptrs ~ 65) and epilogue (33 keys + masks ~ 70) both
// fit WITHOUT spill (rounds 4/5: the (512,8) 64-reg budget spilled ~50MB to
// scratch and erased the occupancy gain). LDS 35.3 KB; registers limit to
// 3 blocks/CU = 24 waves = 1.5x round-3 TLP. Structure = round 4 (best clean
// codegen): x->LDS bf16 prologue, 2-rowset x 4-5-tile GEMM, z->LDS bf16,
// single-pass epilogue (loss+keys), tie-free integer bisection, DPP reductions.
template<bool PRE>
__global__ __launch_bounds__(512, 6)
void fused_mfma_bce_topk(const float* __restrict__ x, const float* __restrict__ y,
                         const float* __restrict__ W, const short* __restrict__ Wbf,
                         const float* __restrict__ bias, const float* __restrict__ pw,
                         float* __restrict__ accum) {
  __shared__ __attribute__((aligned(16))) unsigned short zs_h[BM][ZSH]; // 35,328 B
  __shared__ float redL[8], redS[8];

  const int tid  = threadIdx.x;
  const int w    = tid >> 6, lane = tid & 63;
  const int cl   = lane & 15, quad = lane >> 4;
  const int row0 = blockIdx.x * BM;

  // ---------------- x -> LDS as bf16 (coalesced) ----------------
  unsigned short* xs = &zs_h[0][0];   // [BM][XST] bf16 stage, 33,280 B (unions)
  {
    const float* xblk = x + (size_t)row0 * DD;
#pragma unroll
    for (int i = 0; i < 8; ++i) {
      const int e = i * 2048 + tid * 4;        // f32 element index in 32x512 tile
      f32x4 v = *(const f32x4*)(xblk + e);
      const int r = e >> 9, c = e & 511;
      bf16x4 bv;
      bv[0] = f2bf(v.x); bv[1] = f2bf(v.y); bv[2] = f2bf(v.z); bv[3] = f2bf(v.w);
      *(bf16x4*)(xs + r * XST + c) = bv;       // ds_write_b64
    }
  }
  __syncthreads();

  // tile ranges: wave 0 -> [0,5), wave w>=1 -> [4w+1, 4w+5); 33 tiles total
  const int t0  = (w == 0) ? 0 : 4 * w + 1;
  const bool nt5 = (w == 0);

#define DECL(j) f32x4 P##j = (f32x4){0.f,0.f,0.f,0.f}; f32x4 Q##j = (f32x4){0.f,0.f,0.f,0.f};
  TJ4(DECL) DECL(4)
#undef DECL

  // ---------------- MFMA GEMM over K = 512 (A from LDS) ----------------
  const unsigned short* xr0 = xs + (size_t)cl * XST + quad * 8;          // rowset 0
  const unsigned short* xr1 = xs + (size_t)(16 + cl) * XST + quad * 8;   // rowset 1

  if (PRE) {
#define WB(j) const short* wb##j = Wbf + (size_t)((t0 + (j)) * 16 + cl) * DD + quad * 8;
    TJ4(WB) WB(4)
#undef WB
#define GSTEP(j) { \
    bf16x8 bfr = *(const bf16x8*)(wb##j + k0); \
    P##j = __builtin_amdgcn_mfma_f32_16x16x32_bf16(a0, bfr, P##j, 0, 0, 0); \
    Q##j = __builtin_amdgcn_mfma_f32_16x16x32_bf16(a1, bfr, Q##j, 0, 0, 0); }
    for (int k0 = 0; k0 < DD; k0 += 32) {
      bf16x8 a0 = *(const bf16x8*)(xr0 + k0);
      bf16x8 a1 = *(const bf16x8*)(xr1 + k0);
      TJ4(GSTEP)
      if (nt5) { GSTEP(4) }
    }
#undef GSTEP
  } else {
#define GSTEPF(j) { \
    int col = (t0 + (j)) * 16 + cl; \
    bf16x8 bfr = {0,0,0,0,0,0,0,0}; \
    if (col < CC) { \
      const float* wp = W + (size_t)col * DD + k0 + quad * 8; \
      bfr = pack8(*(const f32x4*)wp, *(const f32x4*)(wp + 4)); \
    } \
    P##j = __builtin_amdgcn_mfma_f32_16x16x32_bf16(a0, bfr, P##j, 0, 0, 0); \
    Q##j = __builtin_amdgcn_mfma_f32_16x16x32_bf16(a1, bfr, Q##j, 0, 0, 0); }
    for (int k0 = 0; k0 < DD; k0 += 32) {
      bf16x8 a0 = *(const bf16x8*)(xr0 + k0);
      bf16x8 a1 = *(const bf16x8*)(xr1 + k0);
      TJ4(GSTEPF)
      if (nt5) { GSTEPF(4) }
    }
#undef GSTEPF
  }

  // bias per owned tile (transient; overlaps the pre-z-write barrier drain)
#define LB(j) float bt##j = 0.f; { int col = (t0 + (j)) * 16 + cl; if (col < CC) bt##j = bias[col]; }
  TJ4(LB)
  float bt4 = 0.f;
  if (nt5) { bt4 = bias[4 * 16 + cl]; }
#undef LB

  // all A-reads done before zs_h overwrites the x-stage region
  __syncthreads();

  // ---------------- z (+bias) -> LDS as bf16 ----------------
  // C/D layout: col = (t0+j)*16 + cl (<= 527 < ZSH), rows quad*4+r / 16+quad*4+r
#define WRZ(j) { \
    const int col = (t0 + (j)) * 16 + cl; \
    const int rr0 = quad * 4; \
    zs_h[rr0 + 0][col] = (unsigned short)f2bf(P##j[0] + bt##j); \
    zs_h[rr0 + 1][col] = (unsigned short)f2bf(P##j[1] + bt##j); \
    zs_h[rr0 + 2][col] = (unsigned short)f2bf(P##j[2] + bt##j); \
    zs_h[rr0 + 3][col] = (unsigned short)f2bf(P##j[3] + bt##j); \
    zs_h[16 + rr0 + 0][col] = (unsigned short)f2bf(Q##j[0] + bt##j); \
    zs_h[16 + rr0 + 1][col] = (unsigned short)f2bf(Q##j[1] + bt##j); \
    zs_h[16 + rr0 + 2][col] = (unsigned short)f2bf(Q##j[2] + bt##j); \
    zs_h[16 + rr0 + 3][col] = (unsigned short)f2bf(Q##j[3] + bt##j); }
  TJ4(WRZ)
  if (nt5) { WRZ(4) }
#undef WRZ

  __syncthreads();

  // ---------------- per-16-lane-group epilogue ----------------
  // group (w,quad) owns row erow; lane cl owns cols {128t+8cl..+7, t<4} + tail 512+cl
  const int erow = w * 4 + quad;                 // 0..31
  const float* yrow = y + (size_t)(row0 + erow) * CC;

#define KDECL(t) int K##t##_0, K##t##_1, K##t##_2, K##t##_3, K##t##_4, K##t##_5, K##t##_6, K##t##_7;
  C4(KDECL)
#undef KDECL
  int K32 = 0;
  unsigned ym0 = 0, ym1 = 0;
  float lossloc = 0.f;

  // loss + keys + positive-mask, one pass per chunk (8 cols/lane/chunk)
#define LE(t, e) { \
    unsigned b = (((e) & 1) ? (zr[(e) >> 1] >> 16) : (zr[(e) >> 1] & 0xFFFFu)); \
    float z = __uint_as_float(b << 16); \
    float yv = ((e) < 4) ? ya[(e)] : yb[(e) - 4]; \
    float pv = ((e) < 4) ? pa[(e)] : pb[(e) - 4]; \
    float l1 = LOG2F(1.f + EXP2F(fabsf(z) * -1.4426950408889634f)) * 0.6931471805599453f; \
    float sp = fmaxf(z, 0.f) + l1; \
    lossloc += pv * yv * (sp - z) + (1.f - yv) * sp; \
    if (yv > 0.5f) ym0 |= (1u << (8*(t)+(e))); \
    K##t##_##e = KEYOF(b, 128*(t) + 8*cl + (e)); }
#define LCH(t) { \
    u32x4 zr = *(const u32x4*)&zs_h[erow][128*(t) + 8*cl]; \
    f32x4 ya = (f32x4)(*(const f32x4u*)(yrow + 128*(t) + 8*cl)); \
    f32x4 yb = (f32x4)(*(const f32x4u*)(yrow + 128*(t) + 8*cl + 4)); \
    f32x4 pa = *(const f32x4*)(pw + 128*(t) + 8*cl); \
    f32x4 pb = *(const f32x4*)(pw + 128*(t) + 8*cl + 4); \
    LE(t,0) LE(t,1) LE(t,2) LE(t,3) LE(t,4) LE(t,5) LE(t,6) LE(t,7) }
  C4(LCH)
#undef LCH
#undef LE
  if (cl < 15) {              // tail cols 512..526
    const int col = 512 + cl;
    unsigned b = zs_h[erow][col];
    float z = __uint_as_float(b << 16);
    float yv = yrow[col];
    float pv = pw[col];
    float l1 = LOG2F(1.f + EXP2F(fabsf(z) * -1.4426950408889634f)) * 0.6931471805599453f;
    float sp = fmaxf(z, 0.f) + l1;
    lossloc += pv * yv * (sp - z) + (1.f - yv) * sp;
    if (yv > 0.5f) ym1 = 1u;
    K32 = KEYOF(b, col);
  }

  const int kk = dppadd16(__popc(ym0) + (int)ym1);

  // bracket: [-1, max-key]; integer bisection, exact count match guaranteed
  int mxK = K32;
#define MXK(t) { int m01 = K##t##_0 > K##t##_1 ? K##t##_0 : K##t##_1; \
    int m23 = K##t##_2 > K##t##_3 ? K##t##_2 : K##t##_3; \
    int m45 = K##t##_4 > K##t##_5 ? K##t##_4 : K##t##_5; \
    int m67 = K##t##_6 > K##t##_7 ? K##t##_6 : K##t##_7; \
    int ma = m01 > m23 ? m01 : m23; int mb = m45 > m67 ? m45 : m67; \
    int mc = ma > mb ? ma : mb; mxK = mxK > mc ? mxK : mc; }
  C4(MXK)
#undef MXK
  mxK = dppmax16i(mxK);

  int lo = -1, hi = mxK, th = 0;
  bool fnd = false;
#pragma unroll 1
  for (int it = 0; it < 32; ++it) {
    const int tm = (lo + hi) >> 1;
    int c = (K32 > tm);
#define CK(t) c += (K##t##_0 > tm) + (K##t##_1 > tm) + (K##t##_2 > tm) + (K##t##_3 > tm) \
             + (K##t##_4 > tm) + (K##t##_5 > tm) + (K##t##_6 > tm) + (K##t##_7 > tm);
    C4(CK)
#undef CK
    c = dppadd16(c);
    if (!fnd) {
      if (c == kk)                   { th = tm; fnd = true; }
      else if (tm <= lo || tm >= hi) { th = lo; fnd = true; }
      else if (c > kk)               lo = tm;
      else                           hi = tm;
    }
    if (__all(fnd)) break;
  }
  if (!fnd) th = lo;

  // hits among positives: decision = key > th
  int h = (int)(ym1 & (unsigned)(K32 > th));
#define HT(t) h += (int)((ym0 >> (8*(t)+0)) & 1u) & (int)(K##t##_0 > th); \
  h += (int)((ym0 >> (8*(t)+1)) & 1u) & (int)(K##t##_1 > th); \
  h += (int)((ym0 >> (8*(t)+2)) & 1u) & (int)(K##t##_2 > th); \
  h += (int)((ym0 >> (8*(t)+3)) & 1u) & (int)(K##t##_3 > th); \
  h += (int)((ym0 >> (8*(t)+4)) & 1u) & (int)(K##t##_4 > th); \
  h += (int)((ym0 >> (8*(t)+5)) & 1u) & (int)(K##t##_5 > th); \
  h += (int)((ym0 >> (8*(t)+6)) & 1u) & (int)(K##t##_6 > th); \
  h += (int)((ym0 >> (8*(t)+7)) & 1u) & (int)(K##t##_7 > th);
  C4(HT)
#undef HT
  h = dppadd16(h);

  float scoreloc = 0.f;
  if (cl == 0) {
    const int hv = h < kk ? h : kk;   // safety clamp
    scoreloc = (float)hv / (float)kk;
  }

  // loss+score: wave butterfly; block: LDS + one atomic per block per output
#pragma unroll
  for (int m = 1; m < 64; m <<= 1) {
    lossloc  += __shfl_xor(lossloc, m, 64);
    scoreloc += __shfl_xor(scoreloc, m, 64);
  }
  if (lane == 0) { redL[w] = lossloc; redS[w] = scoreloc; }
  __syncthreads();
  if (tid == 0) {
    float sl = 0.f, ss = 0.f;
#pragma unroll
    for (int i = 0; i < 8; ++i) { sl += redL[i]; ss += redS[i]; }
    atomicAdd(&accum[0], sl);
    atomicAdd(&accum[1], ss);
  }
}

__global__ void wcvt_kernel(const float* __restrict__ W, short* __restrict__ Wbf,
                            float* __restrict__ ws) {
  if (blockIdx.x == 0 && threadIdx.x == 0) { ws[0] = 0.f; ws[1] = 0.f; }
  int idx = (blockIdx.x * 256 + threadIdx.x) * 4;   // elem in [576*512]
  int row = idx >> 9;
  bf16x4 v = {0, 0, 0, 0};
  if (row < CC) {
    f32x4 f = *(const f32x4*)(W + idx);
    v[0]=f2bf(f.x); v[1]=f2bf(f.y); v[2]=f2bf(f.z); v[3]=f2bf(f.w);
  }
  *(bf16x4*)(Wbf + idx) = v;
}

__global__ void init_ws_kernel(float* ws) {
  ws[0] = 0.f;
  ws[1] = 0.f;
}

__global__ void finalize_kernel(const float* __restrict__ ws, float* __restrict__ out) {
  out[0] = (float)((double)ws[0] / ((double)BB * (double)CC));
  out[1] = (float)((double)ws[1] / (double)BB);
}

extern "C" void kernel_launch(void* const* d_in, const int* in_sizes, int n_in,
                              void* d_out, int out_size, void* d_ws, size_t ws_size,
                              hipStream_t stream) {
  const float* x  = (const float*)d_in[0];
  const float* y  = (const float*)d_in[1];
  const float* W  = (const float*)d_in[2];
  const float* b  = (const float*)d_in[3];
  const float* pw = (const float*)d_in[4];
  float* out = (float*)d_out;
  float* ws  = (float*)d_ws;
  short* Wbf = (short*)((char*)d_ws + 64);

  const size_t need = 64 + (size_t)NCOLP * DD * 2;
  const bool pre = (ws_size >= need);

  if (pre) {
    wcvt_kernel<<<dim3(NCOLP * DD / 1024), dim3(256), 0, stream>>>(W, Wbf, ws);
    fused_mfma_bce_topk<true><<<dim3(BB / BM), dim3(512), 0, stream>>>(
        x, y, W, Wbf, b, pw, ws);
  } else {
    init_ws_kernel<<<dim3(1), dim3(1), 0, stream>>>(ws);
    fused_mfma_bce_topk<false><<<dim3(BB / BM), dim3(512), 0, stream>>>(
        x, y, W, Wbf, b, pw, ws);
  }
  finalize_kernel<<<dim3(1), dim3(1), 0, stream>>>(ws, out);
}

// Round 7
// 227.855 us; speedup vs baseline: 1.1389x; 1.1164x over previous
//
#include <hip/hip_runtime.h>
#include <math.h>

#define BB 32768
#define DD 512
#define CC 527
#define NCOLP 576   // padded W cols in Wbf (layout unchanged; only 33 tiles read)
#define BM 64       // rows per block
#define ZSH 552     // LDS z row stride (u16): 1104 B, 16B-aligned
#define XST 520     // LDS x row stride (bf16): 1040 B -> conflict-free frag reads
#define XBYTES (BM * XST * 2)       // 66,560
#define ZBYTES (BM * ZSH * 2)       // 70,656
#define SMEMB  (XBYTES + ZBYTES)    // 137,216 dynamic LDS (gfx950 has 160K/CU)

typedef __attribute__((ext_vector_type(8))) short bf16x8;
typedef __attribute__((ext_vector_type(4))) short bf16x4;
typedef __attribute__((ext_vector_type(4))) float f32x4;
typedef __attribute__((ext_vector_type(4))) unsigned int u32x4;
typedef f32x4 f32x4u __attribute__((aligned(4)));   // y rows only 4B-aligned (527 odd)

#define C4(OP)  OP(0) OP(1) OP(2) OP(3)

#if __has_builtin(__builtin_amdgcn_exp2f)
#define EXP2F(v) __builtin_amdgcn_exp2f(v)
#else
#define EXP2F(v) exp2f(v)
#endif
#if __has_builtin(__builtin_amdgcn_logf)
#define LOG2F(v) __builtin_amdgcn_logf(v)
#else
#define LOG2F(v) __log2f(v)
#endif

__device__ __forceinline__ short f2bf(float f) {  // fp32 -> bf16 RNE
  unsigned u = __float_as_uint(f);
  u += 0x7fffu + ((u >> 16) & 1u);
  return (short)(u >> 16);
}
__device__ __forceinline__ bf16x8 pack8(f32x4 a, f32x4 b) {
  bf16x8 v;
  v[0]=f2bf(a.x); v[1]=f2bf(a.y); v[2]=f2bf(a.z); v[3]=f2bf(a.w);
  v[4]=f2bf(b.x); v[5]=f2bf(b.y); v[6]=f2bf(b.z); v[7]=f2bf(b.w);
  return v;
}

// 16-lane (DPP row) reductions: 4 x row_ror, pure VALU, no LDS pipe.
__device__ __forceinline__ int dppadd16(int v) {
  v += __builtin_amdgcn_update_dpp(0, v, 0x121, 0xf, 0xf, false);
  v += __builtin_amdgcn_update_dpp(0, v, 0x122, 0xf, 0xf, false);
  v += __builtin_amdgcn_update_dpp(0, v, 0x124, 0xf, 0xf, false);
  v += __builtin_amdgcn_update_dpp(0, v, 0x128, 0xf, 0xf, false);
  return v;
}
__device__ __forceinline__ int dppmax16i(int v) {
  int t;
  t = __builtin_amdgcn_update_dpp(0, v, 0x121, 0xf, 0xf, false); v = v > t ? v : t;
  t = __builtin_amdgcn_update_dpp(0, v, 0x122, 0xf, 0xf, false); v = v > t ? v : t;
  t = __builtin_amdgcn_update_dpp(0, v, 0x124, 0xf, 0xf, false); v = v > t ? v : t;
  t = __builtin_amdgcn_update_dpp(0, v, 0x128, 0xf, 0xf, false); v = v > t ? v : t;
  return v;
}

// bf16 bits -> order-preserving u16, then (mono<<10)|col: strict total order,
// no ties -> integer bisection always terminates on exact count match.
#define KEYOF(b, idx) ((int)(((((unsigned)(b)) ^ (0x8000u | (0xFFFFu * (((unsigned)(b)) >> 15)))) << 10) | (unsigned)(idx)))

// BM=64, 1024 thr = 16 waves, dynamic LDS 137KB (x-stage 66.5K + z 70.7K,
// separate regions -> no union hazard). GEMM: wave = 2 col-tiles x 4 rowsets
// (wave 15 takes tile 32 too: 33 tiles cover C=527) -> each B-load feeds 4
// MFMAs; per-wave VMEM ~68 vs ~108 (r2->r3 law: stall ~ VMEM instr count;
// occupancy 41/51/80% all measured equal -> TLP not the lever). launch_bounds
// (1024,4) = 128-reg budget; peak live ~100 -> no spill (r4/r5 lesson).
// Epilogue: verified r6 code; 64 groups of 16 lanes, one row each; y
// prefetched to regs before z-write; tie-free integer-key bisection, DPP-only.
template<bool PRE>
__global__ __launch_bounds__(1024, 4)
void fused_mfma_bce_topk(const float* __restrict__ x, const float* __restrict__ y,
                         const float* __restrict__ W, const short* __restrict__ Wbf,
                         const float* __restrict__ bias, const float* __restrict__ pw,
                         float* __restrict__ accum) {
  extern __shared__ __align__(16) char smem[];
  unsigned short* xs = (unsigned short*)smem;              // [BM][XST] bf16
  unsigned short* zs = (unsigned short*)(smem + XBYTES);   // [BM][ZSH] bf16
  __shared__ float redL[16], redS[16];

  const int tid  = threadIdx.x;
  const int w    = tid >> 6, lane = tid & 63;
  const int cl   = lane & 15, quad = lane >> 4;
  const int row0 = blockIdx.x * BM;

  // ---------------- x -> LDS as bf16 (coalesced) ----------------
  {
    const float* xblk = x + (size_t)row0 * DD;
#pragma unroll
    for (int i = 0; i < 8; ++i) {
      const int e = i * 4096 + tid * 4;        // f32 elem index in 64x512 tile
      f32x4 v = *(const f32x4*)(xblk + e);
      const int r = e >> 9, c = e & 511;
      bf16x4 bv;
      bv[0] = f2bf(v.x); bv[1] = f2bf(v.y); bv[2] = f2bf(v.z); bv[3] = f2bf(v.w);
      *(bf16x4*)(xs + r * XST + c) = bv;
    }
  }
  __syncthreads();

  // wave w owns col-tiles {2w, 2w+1}; wave 15 also tile 32 (cols 512-527)
  const bool t3 = (w == 15);
  const int c0 = (2 * w) * 16 + cl;   // < 512 always
  const int c1 = c0 + 16;             // <= 511 always
  const int c2 = 512 + cl;            // tile 32 col (valid < CC iff cl < 15)

#define DECLT(j) f32x4 P##j##0 = (f32x4){0.f,0.f,0.f,0.f}; \
                 f32x4 P##j##1 = (f32x4){0.f,0.f,0.f,0.f}; \
                 f32x4 P##j##2 = (f32x4){0.f,0.f,0.f,0.f}; \
                 f32x4 P##j##3 = (f32x4){0.f,0.f,0.f,0.f};
  DECLT(0) DECLT(1) DECLT(2)
#undef DECLT

#define MFT(j, bj) { \
    P##j##0 = __builtin_amdgcn_mfma_f32_16x16x32_bf16(a0, bj, P##j##0, 0, 0, 0); \
    P##j##1 = __builtin_amdgcn_mfma_f32_16x16x32_bf16(a1, bj, P##j##1, 0, 0, 0); \
    P##j##2 = __builtin_amdgcn_mfma_f32_16x16x32_bf16(a2, bj, P##j##2, 0, 0, 0); \
    P##j##3 = __builtin_amdgcn_mfma_f32_16x16x32_bf16(a3, bj, P##j##3, 0, 0, 0); }

  // ---------------- MFMA GEMM over K = 512 (A from LDS, 4 rowsets) ----------
  const unsigned short* xr = xs + (size_t)cl * XST + quad * 8;

  if (PRE) {
    const short* wb0 = Wbf + (size_t)c0 * DD + quad * 8;
    const short* wb1 = Wbf + (size_t)c1 * DD + quad * 8;
    const short* wb2 = Wbf + (size_t)c2 * DD + quad * 8;
    for (int k0 = 0; k0 < DD; k0 += 32) {
      bf16x8 a0 = *(const bf16x8*)(xr + k0);
      bf16x8 a1 = *(const bf16x8*)(xr + 16 * XST + k0);
      bf16x8 a2 = *(const bf16x8*)(xr + 32 * XST + k0);
      bf16x8 a3 = *(const bf16x8*)(xr + 48 * XST + k0);
      bf16x8 b0 = *(const bf16x8*)(wb0 + k0);
      bf16x8 b1 = *(const bf16x8*)(wb1 + k0);
      MFT(0, b0)
      MFT(1, b1)
      if (t3) {
        bf16x8 b2 = *(const bf16x8*)(wb2 + k0);   // Wbf rows >= CC are zeroed
        MFT(2, b2)
      }
    }
  } else {
    for (int k0 = 0; k0 < DD; k0 += 32) {
      bf16x8 a0 = *(const bf16x8*)(xr + k0);
      bf16x8 a1 = *(const bf16x8*)(xr + 16 * XST + k0);
      bf16x8 a2 = *(const bf16x8*)(xr + 32 * XST + k0);
      bf16x8 a3 = *(const bf16x8*)(xr + 48 * XST + k0);
      bf16x8 b0, b1;
      { const float* wp = W + (size_t)c0 * DD + k0 + quad * 8;
        b0 = pack8(*(const f32x4*)wp, *(const f32x4*)(wp + 4)); }
      { const float* wp = W + (size_t)c1 * DD + k0 + quad * 8;
        b1 = pack8(*(const f32x4*)wp, *(const f32x4*)(wp + 4)); }
      MFT(0, b0)
      MFT(1, b1)
      if (t3) {
        bf16x8 b2 = {0,0,0,0,0,0,0,0};
        if (c2 < CC) {
          const float* wp = W + (size_t)c2 * DD + k0 + quad * 8;
          b2 = pack8(*(const f32x4*)wp, *(const f32x4*)(wp + 4));
        }
        MFT(2, b2)
      }
    }
  }
#undef MFT

  // ---------------- epilogue geometry + y prefetch (regs, hidden under WRZ) --
  const int erow = w * 4 + quad;                 // 0..63
  const float* yrow = y + (size_t)(row0 + erow) * CC;
#define LYP(t) f32x4 YA##t = (f32x4)(*(const f32x4u*)(yrow + 128*(t) + 8*cl)); \
               f32x4 YB##t = (f32x4)(*(const f32x4u*)(yrow + 128*(t) + 8*cl + 4));
  C4(LYP)
#undef LYP
  float ytail = (cl < 15) ? yrow[512 + cl] : 0.f;

  // bias per owned tile (cols < 512 always valid; tile 32 guarded)
  const float bt0 = bias[c0];
  const float bt1 = bias[c1];
  const float bt2 = (cl < 15) ? bias[c2] : 0.f;

  // ---------------- z (+bias) -> LDS as bf16 (zs disjoint from xs) ----------
#define WR1(j, s, r, colv, btv) \
  zs[((s) * 16 + quad * 4 + (r)) * ZSH + (colv)] = (unsigned short)f2bf(P##j##s[(r)] + (btv));
#define WRS(j, s, colv, btv) WR1(j,s,0,colv,btv) WR1(j,s,1,colv,btv) WR1(j,s,2,colv,btv) WR1(j,s,3,colv,btv)
#define WRT(j, colv, btv)    WRS(j,0,colv,btv) WRS(j,1,colv,btv) WRS(j,2,colv,btv) WRS(j,3,colv,btv)
  WRT(0, c0, bt0)
  WRT(1, c1, bt1)
  if (t3) { WRT(2, c2, bt2) }   // col 527: acc=0 (zeroed Wbf row), bt2=0 -> z=0
#undef WRT
#undef WRS
#undef WR1

  __syncthreads();

  // ---------------- per-16-lane-group epilogue (r6-verified) ----------------
  const unsigned short* zrow = zs + (size_t)erow * ZSH;

#define KDECL(t) int K##t##_0, K##t##_1, K##t##_2, K##t##_3, K##t##_4, K##t##_5, K##t##_6, K##t##_7;
  C4(KDECL)
#undef KDECL
  int K32 = 0;
  unsigned ym0 = 0, ym1 = 0;
  float lossloc = 0.f;

  // loss + keys + positive-mask, one pass per chunk (8 cols/lane/chunk)
#define LE(t, e) { \
    unsigned b = (((e) & 1) ? (zr[(e) >> 1] >> 16) : (zr[(e) >> 1] & 0xFFFFu)); \
    float z = __uint_as_float(b << 16); \
    float yv = ((e) < 4) ? YA##t[(e)] : YB##t[(e) - 4]; \
    float pv = ((e) < 4) ? pa[(e)] : pb[(e) - 4]; \
    float l1 = LOG2F(1.f + EXP2F(fabsf(z) * -1.4426950408889634f)) * 0.6931471805599453f; \
    float sp = fmaxf(z, 0.f) + l1; \
    lossloc += pv * yv * (sp - z) + (1.f - yv) * sp; \
    if (yv > 0.5f) ym0 |= (1u << (8*(t)+(e))); \
    K##t##_##e = KEYOF(b, 128*(t) + 8*cl + (e)); }
#define LCH(t) { \
    u32x4 zr = *(const u32x4*)&zrow[128*(t) + 8*cl]; \
    f32x4 pa = *(const f32x4*)(pw + 128*(t) + 8*cl); \
    f32x4 pb = *(const f32x4*)(pw + 128*(t) + 8*cl + 4); \
    LE(t,0) LE(t,1) LE(t,2) LE(t,3) LE(t,4) LE(t,5) LE(t,6) LE(t,7) }
  C4(LCH)
#undef LCH
#undef LE
  if (cl < 15) {              // tail cols 512..526
    const int col = 512 + cl;
    unsigned b = zrow[col];
    float z = __uint_as_float(b << 16);
    float yv = ytail;
    float pv = pw[col];
    float l1 = LOG2F(1.f + EXP2F(fabsf(z) * -1.4426950408889634f)) * 0.6931471805599453f;
    float sp = fmaxf(z, 0.f) + l1;
    lossloc += pv * yv * (sp - z) + (1.f - yv) * sp;
    if (yv > 0.5f) ym1 = 1u;
    K32 = KEYOF(b, col);
  }

  const int kk = dppadd16(__popc(ym0) + (int)ym1);

  // bracket: [-1, max-key]; integer bisection, exact count match guaranteed
  int mxK = K32;
#define MXK(t) { int m01 = K##t##_0 > K##t##_1 ? K##t##_0 : K##t##_1; \
    int m23 = K##t##_2 > K##t##_3 ? K##t##_2 : K##t##_3; \
    int m45 = K##t##_4 > K##t##_5 ? K##t##_4 : K##t##_5; \
    int m67 = K##t##_6 > K##t##_7 ? K##t##_6 : K##t##_7; \
    int ma = m01 > m23 ? m01 : m23; int mb = m45 > m67 ? m45 : m67; \
    int mc = ma > mb ? ma : mb; mxK = mxK > mc ? mxK : mc; }
  C4(MXK)
#undef MXK
  mxK = dppmax16i(mxK);

  int lo = -1, hi = mxK, th = 0;
  bool fnd = false;
#pragma unroll 1
  for (int it = 0; it < 32; ++it) {
    const int tm = (lo + hi) >> 1;
    int c = (K32 > tm);
#define CK(t) c += (K##t##_0 > tm) + (K##t##_1 > tm) + (K##t##_2 > tm) + (K##t##_3 > tm) \
             + (K##t##_4 > tm) + (K##t##_5 > tm) + (K##t##_6 > tm) + (K##t##_7 > tm);
    C4(CK)
#undef CK
    c = dppadd16(c);
    if (!fnd) {
      if (c == kk)                   { th = tm; fnd = true; }
      else if (tm <= lo || tm >= hi) { th = lo; fnd = true; }
      else if (c > kk)               lo = tm;
      else                           hi = tm;
    }
    if (__all(fnd)) break;
  }
  if (!fnd) th = lo;

  // hits among positives: decision = key > th
  int h = (int)(ym1 & (unsigned)(K32 > th));
#define HT(t) h += (int)((ym0 >> (8*(t)+0)) & 1u) & (int)(K##t##_0 > th); \
  h += (int)((ym0 >> (8*(t)+1)) & 1u) & (int)(K##t##_1 > th); \
  h += (int)((ym0 >> (8*(t)+2)) & 1u) & (int)(K##t##_2 > th); \
  h += (int)((ym0 >> (8*(t)+3)) & 1u) & (int)(K##t##_3 > th); \
  h += (int)((ym0 >> (8*(t)+4)) & 1u) & (int)(K##t##_4 > th); \
  h += (int)((ym0 >> (8*(t)+5)) & 1u) & (int)(K##t##_5 > th); \
  h += (int)((ym0 >> (8*(t)+6)) & 1u) & (int)(K##t##_6 > th); \
  h += (int)((ym0 >> (8*(t)+7)) & 1u) & (int)(K##t##_7 > th);
  C4(HT)
#undef HT
  h = dppadd16(h);

  float scoreloc = 0.f;
  if (cl == 0) {
    const int hv = h < kk ? h : kk;   // safety clamp
    scoreloc = (float)hv / (float)kk;
  }

  // loss+score: wave butterfly; block: LDS + one atomic per block per output
#pragma unroll
  for (int m = 1; m < 64; m <<= 1) {
    lossloc  += __shfl_xor(lossloc, m, 64);
    scoreloc += __shfl_xor(scoreloc, m, 64);
  }
  if (lane == 0) { redL[w] = lossloc; redS[w] = scoreloc; }
  __syncthreads();
  if (tid == 0) {
    float sl = 0.f, ss = 0.f;
#pragma unroll
    for (int i = 0; i < 16; ++i) { sl += redL[i]; ss += redS[i]; }
    atomicAdd(&accum[0], sl);
    atomicAdd(&accum[1], ss);
  }
}

__global__ void wcvt_kernel(const float* __restrict__ W, short* __restrict__ Wbf,
                            float* __restrict__ ws) {
  if (blockIdx.x == 0 && threadIdx.x == 0) { ws[0] = 0.f; ws[1] = 0.f; }
  int idx = (blockIdx.x * 256 + threadIdx.x) * 4;   // elem in [576*512]
  int row = idx >> 9;
  bf16x4 v = {0, 0, 0, 0};
  if (row < CC) {
    f32x4 f = *(const f32x4*)(W + idx);
    v[0]=f2bf(f.x); v[1]=f2bf(f.y); v[2]=f2bf(f.z); v[3]=f2bf(f.w);
  }
  *(bf16x4*)(Wbf + idx) = v;
}

__global__ void init_ws_kernel(float* ws) {
  ws[0] = 0.f;
  ws[1] = 0.f;
}

__global__ void finalize_kernel(const float* __restrict__ ws, float* __restrict__ out) {
  out[0] = (float)((double)ws[0] / ((double)BB * (double)CC));
  out[1] = (float)((double)ws[1] / (double)BB);
}

extern "C" void kernel_launch(void* const* d_in, const int* in_sizes, int n_in,
                              void* d_out, int out_size, void* d_ws, size_t ws_size,
                              hipStream_t stream) {
  const float* x  = (const float*)d_in[0];
  const float* y  = (const float*)d_in[1];
  const float* W  = (const float*)d_in[2];
  const float* b  = (const float*)d_in[3];
  const float* pw = (const float*)d_in[4];
  float* out = (float*)d_out;
  float* ws  = (float*)d_ws;
  short* Wbf = (short*)((char*)d_ws + 64);

  const size_t need = 64 + (size_t)NCOLP * DD * 2;
  const bool pre = (ws_size >= need);

  if (pre) {
    void (*kp)(const float*, const float*, const float*, const short*,
               const float*, const float*, float*) = fused_mfma_bce_topk<true>;
    hipFuncSetAttribute(reinterpret_cast<const void*>(kp),
                        hipFuncAttributeMaxDynamicSharedMemorySize, SMEMB);
    wcvt_kernel<<<dim3(NCOLP * DD / 1024), dim3(256), 0, stream>>>(W, Wbf, ws);
    fused_mfma_bce_topk<true><<<dim3(BB / BM), dim3(1024), SMEMB, stream>>>(
        x, y, W, Wbf, b, pw, ws);
  } else {
    void (*kp)(const float*, const float*, const float*, const short*,
               const float*, const float*, float*) = fused_mfma_bce_topk<false>;
    hipFuncSetAttribute(reinterpret_cast<const void*>(kp),
                        hipFuncAttributeMaxDynamicSharedMemorySize, SMEMB);
    init_ws_kernel<<<dim3(1), dim3(1), 0, stream>>>(ws);
    fused_mfma_bce_topk<false><<<dim3(BB / BM), dim3(1024), SMEMB, stream>>>(
        x, y, W, Wbf, b, pw, ws);
  }
  finalize_kernel<<<dim3(1), dim3(1), 0, stream>>>(ws, out);
}

// Round 8
// 227.750 us; speedup vs baseline: 1.1394x; 1.0005x over previous
//
#include <hip/hip_runtime.h>
#include <math.h>

#define BB 32768
#define DD 512
#define CC 527
#define NCOLP 576   // padded W cols in Wbf (layout unchanged; only 33 tiles read)
#define BM 64       // rows per block
#define ZSH 552     // LDS z row stride (u16): 1104 B, 16B-aligned
#define XST 520     // LDS x row stride (bf16): 1040 B -> conflict-free frag reads
#define XBYTES (BM * XST * 2)       // 66,560
#define ZBYTES (BM * ZSH * 2)       // 70,656
#define SMEMB  (XBYTES + ZBYTES)    // 137,216 dynamic LDS (gfx950 has 160K/CU)

typedef __attribute__((ext_vector_type(8))) short bf16x8;
typedef __attribute__((ext_vector_type(4))) short bf16x4;
typedef __attribute__((ext_vector_type(4))) float f32x4;
typedef __attribute__((ext_vector_type(4))) unsigned int u32x4;
typedef f32x4 f32x4u __attribute__((aligned(4)));   // y rows only 4B-aligned (527 odd)

#define C4(OP)  OP(0) OP(1) OP(2) OP(3)

#if __has_builtin(__builtin_amdgcn_exp2f)
#define EXP2F(v) __builtin_amdgcn_exp2f(v)
#else
#define EXP2F(v) exp2f(v)
#endif
#if __has_builtin(__builtin_amdgcn_logf)
#define LOG2F(v) __builtin_amdgcn_logf(v)
#else
#define LOG2F(v) __log2f(v)
#endif

__device__ __forceinline__ short f2bf(float f) {  // fp32 -> bf16 RNE (fallback path)
  unsigned u = __float_as_uint(f);
  u += 0x7fffu + ((u >> 16) & 1u);
  return (short)(u >> 16);
}
__device__ __forceinline__ bf16x8 pack8(f32x4 a, f32x4 b) {
  bf16x8 v;
  v[0]=f2bf(a.x); v[1]=f2bf(a.y); v[2]=f2bf(a.z); v[3]=f2bf(a.w);
  v[4]=f2bf(b.x); v[5]=f2bf(b.y); v[6]=f2bf(b.z); v[7]=f2bf(b.w);
  return v;
}
// HW packed f32->bf16 RNE: 1 instr per 2 elems (vs 3 VALU/elem manual)
__device__ __forceinline__ unsigned cvtpk(float lo, float hi) {
  unsigned r;
  asm volatile("v_cvt_pk_bf16_f32 %0, %1, %2" : "=v"(r) : "v"(lo), "v"(hi));
  return r;
}

// 16-lane (DPP row) reductions: 4 x row_ror, pure VALU, no LDS pipe.
__device__ __forceinline__ int dppadd16(int v) {
  v += __builtin_amdgcn_update_dpp(0, v, 0x121, 0xf, 0xf, false);
  v += __builtin_amdgcn_update_dpp(0, v, 0x122, 0xf, 0xf, false);
  v += __builtin_amdgcn_update_dpp(0, v, 0x124, 0xf, 0xf, false);
  v += __builtin_amdgcn_update_dpp(0, v, 0x128, 0xf, 0xf, false);
  return v;
}
__device__ __forceinline__ int dppmax16i(int v) {
  int t;
  t = __builtin_amdgcn_update_dpp(0, v, 0x121, 0xf, 0xf, false); v = v > t ? v : t;
  t = __builtin_amdgcn_update_dpp(0, v, 0x122, 0xf, 0xf, false); v = v > t ? v : t;
  t = __builtin_amdgcn_update_dpp(0, v, 0x124, 0xf, 0xf, false); v = v > t ? v : t;
  t = __builtin_amdgcn_update_dpp(0, v, 0x128, 0xf, 0xf, false); v = v > t ? v : t;
  return v;
}

// bf16 bits -> order-preserving u16, then (mono<<10)|col: strict total order,
// no ties -> integer bisection always terminates on exact count match.
#define KEYOF(b, idx) ((int)(((((unsigned)(b)) ^ (0x8000u | (0xFFFFu * (((unsigned)(b)) >> 15)))) << 10) | (unsigned)(idx)))

// BM=64, 1024 thr = 16 waves, dynamic LDS 137KB (1 block/CU -> no cross-block
// overlap; all latency must be hidden in-block). GEMM: wave = 2 col-tiles x 4
// rowsets; tile 32 (cols 512+) split across waves 14/15 (2 rowsets each) to cap
// worst-case regs at 40 acc. B-stream is DEPTH-2 SOFTWARE-PIPELINED (r7 showed
// an ~82us stall block ~ 16 serial vmcnt(0) events/wave on B): MFMA of step k
// consumes B loaded at step k-2. f32->bf16 via v_cvt_pk_bf16_f32 (x-stage and
// z-write): ~200 VALU instrs/thread removed from the pinned ~38us VALU block.
// Epilogue: r6/r7-verified integer-key bisection, DPP-only reductions.
template<bool PRE>
__global__ __launch_bounds__(1024, 4)
void fused_mfma_bce_topk(const float* __restrict__ x, const float* __restrict__ y,
                         const float* __restrict__ W, const short* __restrict__ Wbf,
                         const float* __restrict__ bias, const float* __restrict__ pw,
                         float* __restrict__ accum) {
  extern __shared__ __align__(16) char smem[];
  unsigned short* xs = (unsigned short*)smem;              // [BM][XST] bf16
  unsigned short* zs = (unsigned short*)(smem + XBYTES);   // [BM][ZSH] bf16
  __shared__ float redL[16], redS[16];

  const int tid  = threadIdx.x;
  const int w    = tid >> 6, lane = tid & 63;
  const int cl   = lane & 15, quad = lane >> 4;
  const int row0 = blockIdx.x * BM;

  // ---------------- x -> LDS as bf16 (coalesced, cvt_pk) ----------------
  {
    const float* xblk = x + (size_t)row0 * DD;
#pragma unroll
    for (int i = 0; i < 8; ++i) {
      const int e = i * 4096 + tid * 4;        // f32 elem index in 64x512 tile
      f32x4 v = *(const f32x4*)(xblk + e);
      const int r = e >> 9, c = e & 511;
      const unsigned w0 = cvtpk(v.x, v.y), w1 = cvtpk(v.z, v.w);
      const unsigned long long ww = (unsigned long long)w0 |
                                    ((unsigned long long)w1 << 32);
      *(unsigned long long*)(xs + r * XST + c) = ww;   // ds_write_b64
    }
  }
  __syncthreads();

  // wave w owns col-tiles {2w, 2w+1}; tile 32 split: w14 rowsets {0,1}, w15 {2,3}
  const bool tA = (w == 14), tB = (w == 15);
  const int c0 = (2 * w) * 16 + cl;   // < 512 always
  const int c1 = c0 + 16;             // <= 511 always
  const int c2 = 512 + cl;            // tile 32 col (valid < CC iff cl < 15)

#define DECLT(j) f32x4 P##j##0 = (f32x4){0.f,0.f,0.f,0.f}; \
                 f32x4 P##j##1 = (f32x4){0.f,0.f,0.f,0.f}; \
                 f32x4 P##j##2 = (f32x4){0.f,0.f,0.f,0.f}; \
                 f32x4 P##j##3 = (f32x4){0.f,0.f,0.f,0.f};
  DECLT(0) DECLT(1)
#undef DECLT
  f32x4 Ra = (f32x4){0.f,0.f,0.f,0.f};   // tile-32 half-accs (w14/w15 only)
  f32x4 Rb = (f32x4){0.f,0.f,0.f,0.f};

#define MFT(j, bj) { \
    P##j##0 = __builtin_amdgcn_mfma_f32_16x16x32_bf16(a0, bj, P##j##0, 0, 0, 0); \
    P##j##1 = __builtin_amdgcn_mfma_f32_16x16x32_bf16(a1, bj, P##j##1, 0, 0, 0); \
    P##j##2 = __builtin_amdgcn_mfma_f32_16x16x32_bf16(a2, bj, P##j##2, 0, 0, 0); \
    P##j##3 = __builtin_amdgcn_mfma_f32_16x16x32_bf16(a3, bj, P##j##3, 0, 0, 0); }

  // ---------------- MFMA GEMM over K = 512 (A from LDS, 4 rowsets) ----------
  const unsigned short* xr = xs + (size_t)cl * XST + quad * 8;

  if (PRE) {
    const short* wb0 = Wbf + (size_t)c0 * DD + quad * 8;
    const short* wb1 = Wbf + (size_t)c1 * DD + quad * 8;
    const short* wb2 = Wbf + (size_t)c2 * DD + quad * 8;
    // depth-2 pipeline: preload k=0 and k=32
    bf16x8 b0c = *(const bf16x8*)(wb0);
    bf16x8 b1c = *(const bf16x8*)(wb1);
    bf16x8 b0n = *(const bf16x8*)(wb0 + 32);
    bf16x8 b1n = *(const bf16x8*)(wb1 + 32);
    bf16x8 b2c = {0,0,0,0,0,0,0,0}, b2n = {0,0,0,0,0,0,0,0};
    if (tA || tB) {
      b2c = *(const bf16x8*)(wb2);        // Wbf rows >= CC are zeroed
      b2n = *(const bf16x8*)(wb2 + 32);
    }
#pragma unroll 1
    for (int k0 = 0; k0 < DD; k0 += 32) {
      bf16x8 a0 = *(const bf16x8*)(xr + k0);
      bf16x8 a1 = *(const bf16x8*)(xr + 16 * XST + k0);
      bf16x8 a2 = *(const bf16x8*)(xr + 32 * XST + k0);
      bf16x8 a3 = *(const bf16x8*)(xr + 48 * XST + k0);
      bf16x8 u0 = b0c, u1 = b1c;
      b0c = b0n; b1c = b1n;
      if (k0 < DD - 64) {
        b0n = *(const bf16x8*)(wb0 + k0 + 64);
        b1n = *(const bf16x8*)(wb1 + k0 + 64);
      }
      MFT(0, u0)
      MFT(1, u1)
      if (tA || tB) {
        bf16x8 u2 = b2c;
        b2c = b2n;
        if (k0 < DD - 64) b2n = *(const bf16x8*)(wb2 + k0 + 64);
        if (tA) {
          Ra = __builtin_amdgcn_mfma_f32_16x16x32_bf16(a0, u2, Ra, 0, 0, 0);
          Rb = __builtin_amdgcn_mfma_f32_16x16x32_bf16(a1, u2, Rb, 0, 0, 0);
        } else {
          Ra = __builtin_amdgcn_mfma_f32_16x16x32_bf16(a2, u2, Ra, 0, 0, 0);
          Rb = __builtin_amdgcn_mfma_f32_16x16x32_bf16(a3, u2, Rb, 0, 0, 0);
        }
      }
    }
  } else {
    for (int k0 = 0; k0 < DD; k0 += 32) {
      bf16x8 a0 = *(const bf16x8*)(xr + k0);
      bf16x8 a1 = *(const bf16x8*)(xr + 16 * XST + k0);
      bf16x8 a2 = *(const bf16x8*)(xr + 32 * XST + k0);
      bf16x8 a3 = *(const bf16x8*)(xr + 48 * XST + k0);
      bf16x8 b0, b1;
      { const float* wp = W + (size_t)c0 * DD + k0 + quad * 8;
        b0 = pack8(*(const f32x4*)wp, *(const f32x4*)(wp + 4)); }
      { const float* wp = W + (size_t)c1 * DD + k0 + quad * 8;
        b1 = pack8(*(const f32x4*)wp, *(const f32x4*)(wp + 4)); }
      MFT(0, b0)
      MFT(1, b1)
      if (tA || tB) {
        bf16x8 b2 = {0,0,0,0,0,0,0,0};
        if (c2 < CC) {
          const float* wp = W + (size_t)c2 * DD + k0 + quad * 8;
          b2 = pack8(*(const f32x4*)wp, *(const f32x4*)(wp + 4));
        }
        if (tA) {
          Ra = __builtin_amdgcn_mfma_f32_16x16x32_bf16(a0, b2, Ra, 0, 0, 0);
          Rb = __builtin_amdgcn_mfma_f32_16x16x32_bf16(a1, b2, Rb, 0, 0, 0);
        } else {
          Ra = __builtin_amdgcn_mfma_f32_16x16x32_bf16(a2, b2, Ra, 0, 0, 0);
          Rb = __builtin_amdgcn_mfma_f32_16x16x32_bf16(a3, b2, Rb, 0, 0, 0);
        }
      }
    }
  }
#undef MFT

  // ---------------- epilogue geometry + y prefetch (regs, hidden under WRZ) --
  const int erow = w * 4 + quad;                 // 0..63
  const float* yrow = y + (size_t)(row0 + erow) * CC;
#define LYP(t) f32x4 YA##t = (f32x4)(*(const f32x4u*)(yrow + 128*(t) + 8*cl)); \
               f32x4 YB##t = (f32x4)(*(const f32x4u*)(yrow + 128*(t) + 8*cl + 4));
  C4(LYP)
#undef LYP
  float ytail = (cl < 15) ? yrow[512 + cl] : 0.f;

  // bias per owned tile (cols < 512 always valid; tile 32 guarded)
  const float bt0 = bias[c0];
  const float bt1 = bias[c1];
  const float bt2 = ((tA || tB) && cl < 15) ? bias[c2] : 0.f;

  // ---------------- z (+bias) -> LDS as bf16 via cvt_pk ----------------
  // C/D layout: col fixed per tile, row = rbase + quad*4 + r
#define WRP(P, rbase, colv, btv) { \
    const unsigned p01 = cvtpk(P[0] + (btv), P[1] + (btv)); \
    const unsigned p23 = cvtpk(P[2] + (btv), P[3] + (btv)); \
    const int rr = (rbase) + quad * 4; \
    zs[(rr + 0) * ZSH + (colv)] = (unsigned short)p01; \
    zs[(rr + 1) * ZSH + (colv)] = (unsigned short)(p01 >> 16); \
    zs[(rr + 2) * ZSH + (colv)] = (unsigned short)p23; \
    zs[(rr + 3) * ZSH + (colv)] = (unsigned short)(p23 >> 16); }
  WRP(P00, 0, c0, bt0) WRP(P01, 16, c0, bt0) WRP(P02, 32, c0, bt0) WRP(P03, 48, c0, bt0)
  WRP(P10, 0, c1, bt1) WRP(P11, 16, c1, bt1) WRP(P12, 32, c1, bt1) WRP(P13, 48, c1, bt1)
  if (tA)      { WRP(Ra, 0, c2, bt2)  WRP(Rb, 16, c2, bt2) }
  else if (tB) { WRP(Ra, 32, c2, bt2) WRP(Rb, 48, c2, bt2) }
#undef WRP

  __syncthreads();

  // ---------------- per-16-lane-group epilogue (r6/r7-verified) -------------
  const unsigned short* zrow = zs + (size_t)erow * ZSH;

#define KDECL(t) int K##t##_0, K##t##_1, K##t##_2, K##t##_3, K##t##_4, K##t##_5, K##t##_6, K##t##_7;
  C4(KDECL)
#undef KDECL
  int K32 = 0;
  unsigned ym0 = 0, ym1 = 0;
  float lossloc = 0.f;

  // loss + keys + positive-mask, one pass per chunk (8 cols/lane/chunk)
#define LE(t, e) { \
    unsigned b = (((e) & 1) ? (zr[(e) >> 1] >> 16) : (zr[(e) >> 1] & 0xFFFFu)); \
    float z = __uint_as_float(b << 16); \
    float yv = ((e) < 4) ? YA##t[(e)] : YB##t[(e) - 4]; \
    float pv = ((e) < 4) ? pa[(e)] : pb[(e) - 4]; \
    float l1 = LOG2F(1.f + EXP2F(fabsf(z) * -1.4426950408889634f)) * 0.6931471805599453f; \
    float sp = fmaxf(z, 0.f) + l1; \
    lossloc += pv * yv * (sp - z) + (1.f - yv) * sp; \
    if (yv > 0.5f) ym0 |= (1u << (8*(t)+(e))); \
    K##t##_##e = KEYOF(b, 128*(t) + 8*cl + (e)); }
#define LCH(t) { \
    u32x4 zr = *(const u32x4*)&zrow[128*(t) + 8*cl]; \
    f32x4 pa = *(const f32x4*)(pw + 128*(t) + 8*cl); \
    f32x4 pb = *(const f32x4*)(pw + 128*(t) + 8*cl + 4); \
    LE(t,0) LE(t,1) LE(t,2) LE(t,3) LE(t,4) LE(t,5) LE(t,6) LE(t,7) }
  C4(LCH)
#undef LCH
#undef LE
  if (cl < 15) {              // tail cols 512..526
    const int col = 512 + cl;
    unsigned b = zrow[col];
    float z = __uint_as_float(b << 16);
    float yv = ytail;
    float pv = pw[col];
    float l1 = LOG2F(1.f + EXP2F(fabsf(z) * -1.4426950408889634f)) * 0.6931471805599453f;
    float sp = fmaxf(z, 0.f) + l1;
    lossloc += pv * yv * (sp - z) + (1.f - yv) * sp;
    if (yv > 0.5f) ym1 = 1u;
    K32 = KEYOF(b, col);
  }

  const int kk = dppadd16(__popc(ym0) + (int)ym1);

  // bracket: [-1, max-key]; integer bisection, exact count match guaranteed
  int mxK = K32;
#define MXK(t) { int m01 = K##t##_0 > K##t##_1 ? K##t##_0 : K##t##_1; \
    int m23 = K##t##_2 > K##t##_3 ? K##t##_2 : K##t##_3; \
    int m45 = K##t##_4 > K##t##_5 ? K##t##_4 : K##t##_5; \
    int m67 = K##t##_6 > K##t##_7 ? K##t##_6 : K##t##_7; \
    int ma = m01 > m23 ? m01 : m23; int mb = m45 > m67 ? m45 : m67; \
    int mc = ma > mb ? ma : mb; mxK = mxK > mc ? mxK : mc; }
  C4(MXK)
#undef MXK
  mxK = dppmax16i(mxK);

  int lo = -1, hi = mxK, th = 0;
  bool fnd = false;
#pragma unroll 1
  for (int it = 0; it < 32; ++it) {
    const int tm = (lo + hi) >> 1;
    int c = (K32 > tm);
#define CK(t) c += (K##t##_0 > tm) + (K##t##_1 > tm) + (K##t##_2 > tm) + (K##t##_3 > tm) \
             + (K##t##_4 > tm) + (K##t##_5 > tm) + (K##t##_6 > tm) + (K##t##_7 > tm);
    C4(CK)
#undef CK
    c = dppadd16(c);
    if (!fnd) {
      if (c == kk)                   { th = tm; fnd = true; }
      else if (tm <= lo || tm >= hi) { th = lo; fnd = true; }
      else if (c > kk)               lo = tm;
      else                           hi = tm;
    }
    if (__all(fnd)) break;
  }
  if (!fnd) th = lo;

  // hits among positives: decision = key > th
  int h = (int)(ym1 & (unsigned)(K32 > th));
#define HT(t) h += (int)((ym0 >> (8*(t)+0)) & 1u) & (int)(K##t##_0 > th); \
  h += (int)((ym0 >> (8*(t)+1)) & 1u) & (int)(K##t##_1 > th); \
  h += (int)((ym0 >> (8*(t)+2)) & 1u) & (int)(K##t##_2 > th); \
  h += (int)((ym0 >> (8*(t)+3)) & 1u) & (int)(K##t##_3 > th); \
  h += (int)((ym0 >> (8*(t)+4)) & 1u) & (int)(K##t##_4 > th); \
  h += (int)((ym0 >> (8*(t)+5)) & 1u) & (int)(K##t##_5 > th); \
  h += (int)((ym0 >> (8*(t)+6)) & 1u) & (int)(K##t##_6 > th); \
  h += (int)((ym0 >> (8*(t)+7)) & 1u) & (int)(K##t##_7 > th);
  C4(HT)
#undef HT
  h = dppadd16(h);

  float scoreloc = 0.f;
  if (cl == 0) {
    const int hv = h < kk ? h : kk;   // safety clamp
    scoreloc = (float)hv / (float)kk;
  }

  // loss+score: wave butterfly; block: LDS + one atomic per block per output
#pragma unroll
  for (int m = 1; m < 64; m <<= 1) {
    lossloc  += __shfl_xor(lossloc, m, 64);
    scoreloc += __shfl_xor(scoreloc, m, 64);
  }
  if (lane == 0) { redL[w] = lossloc; redS[w] = scoreloc; }
  __syncthreads();
  if (tid == 0) {
    float sl = 0.f, ss = 0.f;
#pragma unroll
    for (int i = 0; i < 16; ++i) { sl += redL[i]; ss += redS[i]; }
    atomicAdd(&accum[0], sl);
    atomicAdd(&accum[1], ss);
  }
}

__global__ void wcvt_kernel(const float* __restrict__ W, short* __restrict__ Wbf,
                            float* __restrict__ ws) {
  if (blockIdx.x == 0 && threadIdx.x == 0) { ws[0] = 0.f; ws[1] = 0.f; }
  int idx = (blockIdx.x * 256 + threadIdx.x) * 4;   // elem in [576*512]
  int row = idx >> 9;
  bf16x4 v = {0, 0, 0, 0};
  if (row < CC) {
    f32x4 f = *(const f32x4*)(W + idx);
    v[0]=f2bf(f.x); v[1]=f2bf(f.y); v[2]=f2bf(f.z); v[3]=f2bf(f.w);
  }
  *(bf16x4*)(Wbf + idx) = v;
}

__global__ void init_ws_kernel(float* ws) {
  ws[0] = 0.f;
  ws[1] = 0.f;
}

__global__ void finalize_kernel(const float* __restrict__ ws, float* __restrict__ out) {
  out[0] = (float)((double)ws[0] / ((double)BB * (double)CC));
  out[1] = (float)((double)ws[1] / (double)BB);
}

extern "C" void kernel_launch(void* const* d_in, const int* in_sizes, int n_in,
                              void* d_out, int out_size, void* d_ws, size_t ws_size,
                              hipStream_t stream) {
  const float* x  = (const float*)d_in[0];
  const float* y  = (const float*)d_in[1];
  const float* W  = (const float*)d_in[2];
  const float* b  = (const float*)d_in[3];
  const float* pw = (const float*)d_in[4];
  float* out = (float*)d_out;
  float* ws  = (float*)d_ws;
  short* Wbf = (short*)((char*)d_ws + 64);

  const size_t need = 64 + (size_t)NCOLP * DD * 2;
  const bool pre = (ws_size >= need);

  if (pre) {
    void (*kp)(const float*, const float*, const float*, const short*,
               const float*, const float*, float*) = fused_mfma_bce_topk<true>;
    hipFuncSetAttribute(reinterpret_cast<const void*>(kp),
                        hipFuncAttributeMaxDynamicSharedMemorySize, SMEMB);
    wcvt_kernel<<<dim3(NCOLP * DD / 1024), dim3(256), 0, stream>>>(W, Wbf, ws);
    fused_mfma_bce_topk<true><<<dim3(BB / BM), dim3(1024), SMEMB, stream>>>(
        x, y, W, Wbf, b, pw, ws);
  } else {
    void (*kp)(const float*, const float*, const float*, const short*,
               const float*, const float*, float*) = fused_mfma_bce_topk<false>;
    hipFuncSetAttribute(reinterpret_cast<const void*>(kp),
                        hipFuncAttributeMaxDynamicSharedMemorySize, SMEMB);
    init_ws_kernel<<<dim3(1), dim3(1), 0, stream>>>(ws);
    fused_mfma_bce_topk<false><<<dim3(BB / BM), dim3(1024), SMEMB, stream>>>(
        x, y, W, Wbf, b, pw, ws);
  }
  finalize_kernel<<<dim3(1), dim3(1), 0, stream>>>(ws, out);
}

// Round 9
// 224.560 us; speedup vs baseline: 1.1556x; 1.0142x over previous
//
#include <hip/hip_runtime.h>
#include <math.h>

#define BB 32768
#define DD 512
#define CC 527
#define NCOLP 576   // padded W cols in Wbf
#define BM 64       // rows per GEMM block
#define ZSH 552     // LDS z row stride (u16): 1104 B, 16B-aligned
#define XST 520     // LDS x row stride (bf16)
#define XBYTES (BM * XST * 2)       // 66,560
#define ZBYTES (BM * ZSH * 2)       // 70,656
#define SMEMB  (XBYTES + ZBYTES)    // 137,216 dynamic LDS
#define ZGS 528     // global z row stride (u16): 1056 B, 16B-aligned

typedef __attribute__((ext_vector_type(8))) short bf16x8;
typedef __attribute__((ext_vector_type(4))) short bf16x4;
typedef __attribute__((ext_vector_type(4))) float f32x4;
typedef __attribute__((ext_vector_type(4))) unsigned int u32x4;
typedef f32x4 f32x4u __attribute__((aligned(4)));   // y rows only 4B-aligned

#define C4(OP)  OP(0) OP(1) OP(2) OP(3)

#if __has_builtin(__builtin_amdgcn_exp2f)
#define EXP2F(v) __builtin_amdgcn_exp2f(v)
#else
#define EXP2F(v) exp2f(v)
#endif
#if __has_builtin(__builtin_amdgcn_logf)
#define LOG2F(v) __builtin_amdgcn_logf(v)
#else
#define LOG2F(v) __log2f(v)
#endif

__device__ __forceinline__ short f2bf(float f) {  // fp32 -> bf16 RNE
  unsigned u = __float_as_uint(f);
  u += 0x7fffu + ((u >> 16) & 1u);
  return (short)(u >> 16);
}
__device__ __forceinline__ bf16x8 pack8(f32x4 a, f32x4 b) {
  bf16x8 v;
  v[0]=f2bf(a.x); v[1]=f2bf(a.y); v[2]=f2bf(a.z); v[3]=f2bf(a.w);
  v[4]=f2bf(b.x); v[5]=f2bf(b.y); v[6]=f2bf(b.z); v[7]=f2bf(b.w);
  return v;
}
__device__ __forceinline__ unsigned cvtpk(float lo, float hi) {
  unsigned r;
  asm volatile("v_cvt_pk_bf16_f32 %0, %1, %2" : "=v"(r) : "v"(lo), "v"(hi));
  return r;
}

// 16-lane (DPP row) reductions: 4 x row_ror, pure VALU.
__device__ __forceinline__ int dppadd16(int v) {
  v += __builtin_amdgcn_update_dpp(0, v, 0x121, 0xf, 0xf, false);
  v += __builtin_amdgcn_update_dpp(0, v, 0x122, 0xf, 0xf, false);
  v += __builtin_amdgcn_update_dpp(0, v, 0x124, 0xf, 0xf, false);
  v += __builtin_amdgcn_update_dpp(0, v, 0x128, 0xf, 0xf, false);
  return v;
}
__device__ __forceinline__ int dppmax16i(int v) {
  int t;
  t = __builtin_amdgcn_update_dpp(0, v, 0x121, 0xf, 0xf, false); v = v > t ? v : t;
  t = __builtin_amdgcn_update_dpp(0, v, 0x122, 0xf, 0xf, false); v = v > t ? v : t;
  t = __builtin_amdgcn_update_dpp(0, v, 0x124, 0xf, 0xf, false); v = v > t ? v : t;
  t = __builtin_amdgcn_update_dpp(0, v, 0x128, 0xf, 0xf, false); v = v > t ? v : t;
  return v;
}

// bf16 bits -> order-preserving u16, then (mono<<10)|col: tie-free total order.
#define KEYOF(b, idx) ((int)(((((unsigned)(b)) ^ (0x8000u | (0xFFFFu * (((unsigned)(b)) >> 15)))) << 10) | (unsigned)(idx)))

// ============================ SPLIT PATH =====================================
// r8 analysis: 1 block/CU fused -> phases strictly serial; epilogue's 40us VALU
// runs at 34% busy with 60% unattributed stall. Split: GEMM pass (r8 GEMM
// verbatim, z -> global bf16 via the existing LDS transpose, coalesced x4) and
// a standalone epilogue pass at 3 blocks/CU (no LDS tile, no acc regs, y
// inline) so its VALU issues at ~2x occupancy and z/y stream from L3.

// ---- pass 1: GEMM (r8 structure, epilogue replaced by z copy-out) ----
__global__ __launch_bounds__(1024, 4)
void gemm_part(const float* __restrict__ x, const short* __restrict__ Wbf,
               const float* __restrict__ bias, unsigned short* __restrict__ zg) {
  extern __shared__ __align__(16) char smem[];
  unsigned short* xs = (unsigned short*)smem;              // [BM][XST] bf16
  unsigned short* zs = (unsigned short*)(smem + XBYTES);   // [BM][ZSH] bf16

  const int tid  = threadIdx.x;
  const int w    = tid >> 6, lane = tid & 63;
  const int cl   = lane & 15, quad = lane >> 4;
  const int row0 = blockIdx.x * BM;

  // x -> LDS as bf16 (coalesced, cvt_pk)
  {
    const float* xblk = x + (size_t)row0 * DD;
#pragma unroll
    for (int i = 0; i < 8; ++i) {
      const int e = i * 4096 + tid * 4;
      f32x4 v = *(const f32x4*)(xblk + e);
      const int r = e >> 9, c = e & 511;
      const unsigned w0 = cvtpk(v.x, v.y), w1 = cvtpk(v.z, v.w);
      const unsigned long long ww = (unsigned long long)w0 |
                                    ((unsigned long long)w1 << 32);
      *(unsigned long long*)(xs + r * XST + c) = ww;
    }
  }
  __syncthreads();

  // wave w owns tiles {2w,2w+1}; tile 32 split: w14 rowsets {0,1}, w15 {2,3}
  const bool tA = (w == 14), tB = (w == 15);
  const int c0 = (2 * w) * 16 + cl;
  const int c1 = c0 + 16;
  const int c2 = 512 + cl;

#define DECLT(j) f32x4 P##j##0 = (f32x4){0.f,0.f,0.f,0.f}; \
                 f32x4 P##j##1 = (f32x4){0.f,0.f,0.f,0.f}; \
                 f32x4 P##j##2 = (f32x4){0.f,0.f,0.f,0.f}; \
                 f32x4 P##j##3 = (f32x4){0.f,0.f,0.f,0.f};
  DECLT(0) DECLT(1)
#undef DECLT
  f32x4 Ra = (f32x4){0.f,0.f,0.f,0.f};
  f32x4 Rb = (f32x4){0.f,0.f,0.f,0.f};

#define MFT(j, bj) { \
    P##j##0 = __builtin_amdgcn_mfma_f32_16x16x32_bf16(a0, bj, P##j##0, 0, 0, 0); \
    P##j##1 = __builtin_amdgcn_mfma_f32_16x16x32_bf16(a1, bj, P##j##1, 0, 0, 0); \
    P##j##2 = __builtin_amdgcn_mfma_f32_16x16x32_bf16(a2, bj, P##j##2, 0, 0, 0); \
    P##j##3 = __builtin_amdgcn_mfma_f32_16x16x32_bf16(a3, bj, P##j##3, 0, 0, 0); }

  const unsigned short* xr = xs + (size_t)cl * XST + quad * 8;
  {
    const short* wb0 = Wbf + (size_t)c0 * DD + quad * 8;
    const short* wb1 = Wbf + (size_t)c1 * DD + quad * 8;
    const short* wb2 = Wbf + (size_t)c2 * DD + quad * 8;
    bf16x8 b0c = *(const bf16x8*)(wb0);
    bf16x8 b1c = *(const bf16x8*)(wb1);
    bf16x8 b0n = *(const bf16x8*)(wb0 + 32);
    bf16x8 b1n = *(const bf16x8*)(wb1 + 32);
    bf16x8 b2c = {0,0,0,0,0,0,0,0}, b2n = {0,0,0,0,0,0,0,0};
    if (tA || tB) {
      b2c = *(const bf16x8*)(wb2);        // Wbf rows >= CC are zeroed
      b2n = *(const bf16x8*)(wb2 + 32);
    }
#pragma unroll 1
    for (int k0 = 0; k0 < DD; k0 += 32) {
      bf16x8 a0 = *(const bf16x8*)(xr + k0);
      bf16x8 a1 = *(const bf16x8*)(xr + 16 * XST + k0);
      bf16x8 a2 = *(const bf16x8*)(xr + 32 * XST + k0);
      bf16x8 a3 = *(const bf16x8*)(xr + 48 * XST + k0);
      bf16x8 u0 = b0c, u1 = b1c;
      b0c = b0n; b1c = b1n;
      if (k0 < DD - 64) {
        b0n = *(const bf16x8*)(wb0 + k0 + 64);
        b1n = *(const bf16x8*)(wb1 + k0 + 64);
      }
      MFT(0, u0)
      MFT(1, u1)
      if (tA || tB) {
        bf16x8 u2 = b2c;
        b2c = b2n;
        if (k0 < DD - 64) b2n = *(const bf16x8*)(wb2 + k0 + 64);
        if (tA) {
          Ra = __builtin_amdgcn_mfma_f32_16x16x32_bf16(a0, u2, Ra, 0, 0, 0);
          Rb = __builtin_amdgcn_mfma_f32_16x16x32_bf16(a1, u2, Rb, 0, 0, 0);
        } else {
          Ra = __builtin_amdgcn_mfma_f32_16x16x32_bf16(a2, u2, Ra, 0, 0, 0);
          Rb = __builtin_amdgcn_mfma_f32_16x16x32_bf16(a3, u2, Rb, 0, 0, 0);
        }
      }
    }
  }
#undef MFT

  const float bt0 = bias[c0];
  const float bt1 = bias[c1];
  const float bt2 = ((tA || tB) && cl < 15) ? bias[c2] : 0.f;

  // z (+bias) -> LDS as bf16 via cvt_pk (transpose)
#define WRP(P, rbase, colv, btv) { \
    const unsigned p01 = cvtpk(P[0] + (btv), P[1] + (btv)); \
    const unsigned p23 = cvtpk(P[2] + (btv), P[3] + (btv)); \
    const int rr = (rbase) + quad * 4; \
    zs[(rr + 0) * ZSH + (colv)] = (unsigned short)p01; \
    zs[(rr + 1) * ZSH + (colv)] = (unsigned short)(p01 >> 16); \
    zs[(rr + 2) * ZSH + (colv)] = (unsigned short)p23; \
    zs[(rr + 3) * ZSH + (colv)] = (unsigned short)(p23 >> 16); }
  WRP(P00, 0, c0, bt0) WRP(P01, 16, c0, bt0) WRP(P02, 32, c0, bt0) WRP(P03, 48, c0, bt0)
  WRP(P10, 0, c1, bt1) WRP(P11, 16, c1, bt1) WRP(P12, 32, c1, bt1) WRP(P13, 48, c1, bt1)
  if (tA)      { WRP(Ra, 0, c2, bt2)  WRP(Rb, 16, c2, bt2) }
  else if (tB) { WRP(Ra, 32, c2, bt2) WRP(Rb, 48, c2, bt2) }
#undef WRP

  __syncthreads();

  // coalesced copy-out: 64 rows x 528 u16 -> zg (row stride ZGS=528)
  // 4224 x4-chunks (66 per row); 16B-aligned both sides.
#pragma unroll
  for (int i = tid; i < 4224; i += 1024) {
    const int r = i / 66, c = i % 66;
    u32x4 v = *(const u32x4*)(zs + r * ZSH + c * 8);
    *(u32x4*)(zg + (size_t)(row0 + r) * ZGS + c * 8) = v;
  }
}

// ---- pass 2: epilogue (r6/r8-verified body; z from global; y inline) ----
__global__ __launch_bounds__(512, 6)
void epi_part(const unsigned short* __restrict__ zg, const float* __restrict__ y,
              const float* __restrict__ pw, float* __restrict__ accum) {
  __shared__ float redL[8], redS[8];
  const int tid  = threadIdx.x;
  const int w    = tid >> 6, lane = tid & 63;
  const int cl   = lane & 15, quad = lane >> 4;
  const int erow = blockIdx.x * 32 + w * 4 + quad;   // one row per 16-lane group

  const unsigned short* zrow = zg + (size_t)erow * ZGS;
  const float* yrow = y + (size_t)erow * CC;

#define KDECL(t) int K##t##_0, K##t##_1, K##t##_2, K##t##_3, K##t##_4, K##t##_5, K##t##_6, K##t##_7;
  C4(KDECL)
#undef KDECL
  int K32 = 0;
  unsigned ym0 = 0, ym1 = 0;
  float lossloc = 0.f;

#define LE(t, e) { \
    unsigned b = (((e) & 1) ? (zr[(e) >> 1] >> 16) : (zr[(e) >> 1] & 0xFFFFu)); \
    float z = __uint_as_float(b << 16); \
    float yv = ((e) < 4) ? ya[(e)] : yb[(e) - 4]; \
    float pv = ((e) < 4) ? pa[(e)] : pb[(e) - 4]; \
    float l1 = LOG2F(1.f + EXP2F(fabsf(z) * -1.4426950408889634f)) * 0.6931471805599453f; \
    float sp = fmaxf(z, 0.f) + l1; \
    lossloc += pv * yv * (sp - z) + (1.f - yv) * sp; \
    if (yv > 0.5f) ym0 |= (1u << (8*(t)+(e))); \
    K##t##_##e = KEYOF(b, 128*(t) + 8*cl + (e)); }
#define LCH(t) { \
    u32x4 zr = *(const u32x4*)&zrow[128*(t) + 8*cl]; \
    f32x4 ya = (f32x4)(*(const f32x4u*)(yrow + 128*(t) + 8*cl)); \
    f32x4 yb = (f32x4)(*(const f32x4u*)(yrow + 128*(t) + 8*cl + 4)); \
    f32x4 pa = *(const f32x4*)(pw + 128*(t) + 8*cl); \
    f32x4 pb = *(const f32x4*)(pw + 128*(t) + 8*cl + 4); \
    LE(t,0) LE(t,1) LE(t,2) LE(t,3) LE(t,4) LE(t,5) LE(t,6) LE(t,7) }
  C4(LCH)
#undef LCH
#undef LE
  if (cl < 15) {              // tail cols 512..526
    const int col = 512 + cl;
    unsigned b = zrow[col];
    float z = __uint_as_float(b << 16);
    float yv = yrow[col];
    float pv = pw[col];
    float l1 = LOG2F(1.f + EXP2F(fabsf(z) * -1.4426950408889634f)) * 0.6931471805599453f;
    float sp = fmaxf(z, 0.f) + l1;
    lossloc += pv * yv * (sp - z) + (1.f - yv) * sp;
    if (yv > 0.5f) ym1 = 1u;
    K32 = KEYOF(b, col);
  }

  const int kk = dppadd16(__popc(ym0) + (int)ym1);

  int mxK = K32;
#define MXK(t) { int m01 = K##t##_0 > K##t##_1 ? K##t##_0 : K##t##_1; \
    int m23 = K##t##_2 > K##t##_3 ? K##t##_2 : K##t##_3; \
    int m45 = K##t##_4 > K##t##_5 ? K##t##_4 : K##t##_5; \
    int m67 = K##t##_6 > K##t##_7 ? K##t##_6 : K##t##_7; \
    int ma = m01 > m23 ? m01 : m23; int mb = m45 > m67 ? m45 : m67; \
    int mc = ma > mb ? ma : mb; mxK = mxK > mc ? mxK : mc; }
  C4(MXK)
#undef MXK
  mxK = dppmax16i(mxK);

  int lo = -1, hi = mxK, th = 0;
  bool fnd = false;
#pragma unroll 1
  for (int it = 0; it < 32; ++it) {
    const int tm = (lo + hi) >> 1;
    int c = (K32 > tm);
#define CK(t) c += (K##t##_0 > tm) + (K##t##_1 > tm) + (K##t##_2 > tm) + (K##t##_3 > tm) \
             + (K##t##_4 > tm) + (K##t##_5 > tm) + (K##t##_6 > tm) + (K##t##_7 > tm);
    C4(CK)
#undef CK
    c = dppadd16(c);
    if (!fnd) {
      if (c == kk)                   { th = tm; fnd = true; }
      else if (tm <= lo || tm >= hi) { th = lo; fnd = true; }
      else if (c > kk)               lo = tm;
      else                           hi = tm;
    }
    if (__all(fnd)) break;
  }
  if (!fnd) th = lo;

  int h = (int)(ym1 & (unsigned)(K32 > th));
#define HT(t) h += (int)((ym0 >> (8*(t)+0)) & 1u) & (int)(K##t##_0 > th); \
  h += (int)((ym0 >> (8*(t)+1)) & 1u) & (int)(K##t##_1 > th); \
  h += (int)((ym0 >> (8*(t)+2)) & 1u) & (int)(K##t##_2 > th); \
  h += (int)((ym0 >> (8*(t)+3)) & 1u) & (int)(K##t##_3 > th); \
  h += (int)((ym0 >> (8*(t)+4)) & 1u) & (int)(K##t##_4 > th); \
  h += (int)((ym0 >> (8*(t)+5)) & 1u) & (int)(K##t##_5 > th); \
  h += (int)((ym0 >> (8*(t)+6)) & 1u) & (int)(K##t##_6 > th); \
  h += (int)((ym0 >> (8*(t)+7)) & 1u) & (int)(K##t##_7 > th);
  C4(HT)
#undef HT
  h = dppadd16(h);

  float scoreloc = 0.f;
  if (cl == 0) {
    const int hv = h < kk ? h : kk;
    scoreloc = (float)hv / (float)kk;
  }

#pragma unroll
  for (int m = 1; m < 64; m <<= 1) {
    lossloc  += __shfl_xor(lossloc, m, 64);
    scoreloc += __shfl_xor(scoreloc, m, 64);
  }
  if (lane == 0) { redL[w] = lossloc; redS[w] = scoreloc; }
  __syncthreads();
  if (tid == 0) {
    float sl = 0.f, ss = 0.f;
#pragma unroll
    for (int i = 0; i < 8; ++i) { sl += redL[i]; ss += redS[i]; }
    atomicAdd(&accum[0], sl);
    atomicAdd(&accum[1], ss);
  }
}

// ======================== FUSED FALLBACK (r8, verified) ======================
template<bool PRE>
__global__ __launch_bounds__(1024, 4)
void fused_mfma_bce_topk(const float* __restrict__ x, const float* __restrict__ y,
                         const float* __restrict__ W, const short* __restrict__ Wbf,
                         const float* __restrict__ bias, const float* __restrict__ pw,
                         float* __restrict__ accum) {
  extern __shared__ __align__(16) char smem[];
  unsigned short* xs = (unsigned short*)smem;
  unsigned short* zs = (unsigned short*)(smem + XBYTES);
  __shared__ float redL[16], redS[16];

  const int tid  = threadIdx.x;
  const int w    = tid >> 6, lane = tid & 63;
  const int cl   = lane & 15, quad = lane >> 4;
  const int row0 = blockIdx.x * BM;

  {
    const float* xblk = x + (size_t)row0 * DD;
#pragma unroll
    for (int i = 0; i < 8; ++i) {
      const int e = i * 4096 + tid * 4;
      f32x4 v = *(const f32x4*)(xblk + e);
      const int r = e >> 9, c = e & 511;
      const unsigned w0 = cvtpk(v.x, v.y), w1 = cvtpk(v.z, v.w);
      const unsigned long long ww = (unsigned long long)w0 |
                                    ((unsigned long long)w1 << 32);
      *(unsigned long long*)(xs + r * XST + c) = ww;
    }
  }
  __syncthreads();

  const bool tA = (w == 14), tB = (w == 15);
  const int c0 = (2 * w) * 16 + cl;
  const int c1 = c0 + 16;
  const int c2 = 512 + cl;

#define DECLT(j) f32x4 P##j##0 = (f32x4){0.f,0.f,0.f,0.f}; \
                 f32x4 P##j##1 = (f32x4){0.f,0.f,0.f,0.f}; \
                 f32x4 P##j##2 = (f32x4){0.f,0.f,0.f,0.f}; \
                 f32x4 P##j##3 = (f32x4){0.f,0.f,0.f,0.f};
  DECLT(0) DECLT(1)
#undef DECLT
  f32x4 Ra = (f32x4){0.f,0.f,0.f,0.f};
  f32x4 Rb = (f32x4){0.f,0.f,0.f,0.f};

#define MFT(j, bj) { \
    P##j##0 = __builtin_amdgcn_mfma_f32_16x16x32_bf16(a0, bj, P##j##0, 0, 0, 0); \
    P##j##1 = __builtin_amdgcn_mfma_f32_16x16x32_bf16(a1, bj, P##j##1, 0, 0, 0); \
    P##j##2 = __builtin_amdgcn_mfma_f32_16x16x32_bf16(a2, bj, P##j##2, 0, 0, 0); \
    P##j##3 = __builtin_amdgcn_mfma_f32_16x16x32_bf16(a3, bj, P##j##3, 0, 0, 0); }

  const unsigned short* xr = xs + (size_t)cl * XST + quad * 8;

  if (PRE) {
    const short* wb0 = Wbf + (size_t)c0 * DD + quad * 8;
    const short* wb1 = Wbf + (size_t)c1 * DD + quad * 8;
    const short* wb2 = Wbf + (size_t)c2 * DD + quad * 8;
    bf16x8 b0c = *(const bf16x8*)(wb0);
    bf16x8 b1c = *(const bf16x8*)(wb1);
    bf16x8 b0n = *(const bf16x8*)(wb0 + 32);
    bf16x8 b1n = *(const bf16x8*)(wb1 + 32);
    bf16x8 b2c = {0,0,0,0,0,0,0,0}, b2n = {0,0,0,0,0,0,0,0};
    if (tA || tB) {
      b2c = *(const bf16x8*)(wb2);
      b2n = *(const bf16x8*)(wb2 + 32);
    }
#pragma unroll 1
    for (int k0 = 0; k0 < DD; k0 += 32) {
      bf16x8 a0 = *(const bf16x8*)(xr + k0);
      bf16x8 a1 = *(const bf16x8*)(xr + 16 * XST + k0);
      bf16x8 a2 = *(const bf16x8*)(xr + 32 * XST + k0);
      bf16x8 a3 = *(const bf16x8*)(xr + 48 * XST + k0);
      bf16x8 u0 = b0c, u1 = b1c;
      b0c = b0n; b1c = b1n;
      if (k0 < DD - 64) {
        b0n = *(const bf16x8*)(wb0 + k0 + 64);
        b1n = *(const bf16x8*)(wb1 + k0 + 64);
      }
      MFT(0, u0)
      MFT(1, u1)
      if (tA || tB) {
        bf16x8 u2 = b2c;
        b2c = b2n;
        if (k0 < DD - 64) b2n = *(const bf16x8*)(wb2 + k0 + 64);
        if (tA) {
          Ra = __builtin_amdgcn_mfma_f32_16x16x32_bf16(a0, u2, Ra, 0, 0, 0);
          Rb = __builtin_amdgcn_mfma_f32_16x16x32_bf16(a1, u2, Rb, 0, 0, 0);
        } else {
          Ra = __builtin_amdgcn_mfma_f32_16x16x32_bf16(a2, u2, Ra, 0, 0, 0);
          Rb = __builtin_amdgcn_mfma_f32_16x16x32_bf16(a3, u2, Rb, 0, 0, 0);
        }
      }
    }
  } else {
    for (int k0 = 0; k0 < DD; k0 += 32) {
      bf16x8 a0 = *(const bf16x8*)(xr + k0);
      bf16x8 a1 = *(const bf16x8*)(xr + 16 * XST + k0);
      bf16x8 a2 = *(const bf16x8*)(xr + 32 * XST + k0);
      bf16x8 a3 = *(const bf16x8*)(xr + 48 * XST + k0);
      bf16x8 b0, b1;
      { const float* wp = W + (size_t)c0 * DD + k0 + quad * 8;
        b0 = pack8(*(const f32x4*)wp, *(const f32x4*)(wp + 4)); }
      { const float* wp = W + (size_t)c1 * DD + k0 + quad * 8;
        b1 = pack8(*(const f32x4*)wp, *(const f32x4*)(wp + 4)); }
      MFT(0, b0)
      MFT(1, b1)
      if (tA || tB) {
        bf16x8 b2 = {0,0,0,0,0,0,0,0};
        if (c2 < CC) {
          const float* wp = W + (size_t)c2 * DD + k0 + quad * 8;
          b2 = pack8(*(const f32x4*)wp, *(const f32x4*)(wp + 4));
        }
        if (tA) {
          Ra = __builtin_amdgcn_mfma_f32_16x16x32_bf16(a0, b2, Ra, 0, 0, 0);
          Rb = __builtin_amdgcn_mfma_f32_16x16x32_bf16(a1, b2, Rb, 0, 0, 0);
        } else {
          Ra = __builtin_amdgcn_mfma_f32_16x16x32_bf16(a2, b2, Ra, 0, 0, 0);
          Rb = __builtin_amdgcn_mfma_f32_16x16x32_bf16(a3, b2, Rb, 0, 0, 0);
        }
      }
    }
  }
#undef MFT

  const int erow = w * 4 + quad;
  const float* yrow = y + (size_t)erow * CC + (size_t)row0 * CC;
#define LYP(t) f32x4 YA##t = (f32x4)(*(const f32x4u*)(yrow + 128*(t) + 8*cl)); \
               f32x4 YB##t = (f32x4)(*(const f32x4u*)(yrow + 128*(t) + 8*cl + 4));
  C4(LYP)
#undef LYP
  float ytail = (cl < 15) ? yrow[512 + cl] : 0.f;

  const float bt0 = bias[c0];
  const float bt1 = bias[c1];
  const float bt2 = ((tA || tB) && cl < 15) ? bias[c2] : 0.f;

#define WRP(P, rbase, colv, btv) { \
    const unsigned p01 = cvtpk(P[0] + (btv), P[1] + (btv)); \
    const unsigned p23 = cvtpk(P[2] + (btv), P[3] + (btv)); \
    const int rr = (rbase) + quad * 4; \
    zs[(rr + 0) * ZSH + (colv)] = (unsigned short)p01; \
    zs[(rr + 1) * ZSH + (colv)] = (unsigned short)(p01 >> 16); \
    zs[(rr + 2) * ZSH + (colv)] = (unsigned short)p23; \
    zs[(rr + 3) * ZSH + (colv)] = (unsigned short)(p23 >> 16); }
  WRP(P00, 0, c0, bt0) WRP(P01, 16, c0, bt0) WRP(P02, 32, c0, bt0) WRP(P03, 48, c0, bt0)
  WRP(P10, 0, c1, bt1) WRP(P11, 16, c1, bt1) WRP(P12, 32, c1, bt1) WRP(P13, 48, c1, bt1)
  if (tA)      { WRP(Ra, 0, c2, bt2)  WRP(Rb, 16, c2, bt2) }
  else if (tB) { WRP(Ra, 32, c2, bt2) WRP(Rb, 48, c2, bt2) }
#undef WRP

  __syncthreads();

  const unsigned short* zrow = zs + (size_t)erow * ZSH;

#define KDECL(t) int K##t##_0, K##t##_1, K##t##_2, K##t##_3, K##t##_4, K##t##_5, K##t##_6, K##t##_7;
  C4(KDECL)
#undef KDECL
  int K32 = 0;
  unsigned ym0 = 0, ym1 = 0;
  float lossloc = 0.f;

#define LE(t, e) { \
    unsigned b = (((e) & 1) ? (zr[(e) >> 1] >> 16) : (zr[(e) >> 1] & 0xFFFFu)); \
    float z = __uint_as_float(b << 16); \
    float yv = ((e) < 4) ? YA##t[(e)] : YB##t[(e) - 4]; \
    float pv = ((e) < 4) ? pa[(e)] : pb[(e) - 4]; \
    float l1 = LOG2F(1.f + EXP2F(fabsf(z) * -1.4426950408889634f)) * 0.6931471805599453f; \
    float sp = fmaxf(z, 0.f) + l1; \
    lossloc += pv * yv * (sp - z) + (1.f - yv) * sp; \
    if (yv > 0.5f) ym0 |= (1u << (8*(t)+(e))); \
    K##t##_##e = KEYOF(b, 128*(t) + 8*cl + (e)); }
#define LCH(t) { \
    u32x4 zr = *(const u32x4*)&zrow[128*(t) + 8*cl]; \
    f32x4 pa = *(const f32x4*)(pw + 128*(t) + 8*cl); \
    f32x4 pb = *(const f32x4*)(pw + 128*(t) + 8*cl + 4); \
    LE(t,0) LE(t,1) LE(t,2) LE(t,3) LE(t,4) LE(t,5) LE(t,6) LE(t,7) }
  C4(LCH)
#undef LCH
#undef LE
  if (cl < 15) {
    const int col = 512 + cl;
    unsigned b = zrow[col];
    float z = __uint_as_float(b << 16);
    float yv = ytail;
    float pv = pw[col];
    float l1 = LOG2F(1.f + EXP2F(fabsf(z) * -1.4426950408889634f)) * 0.6931471805599453f;
    float sp = fmaxf(z, 0.f) + l1;
    lossloc += pv * yv * (sp - z) + (1.f - yv) * sp;
    if (yv > 0.5f) ym1 = 1u;
    K32 = KEYOF(b, col);
  }

  const int kk = dppadd16(__popc(ym0) + (int)ym1);

  int mxK = K32;
#define MXK(t) { int m01 = K##t##_0 > K##t##_1 ? K##t##_0 : K##t##_1; \
    int m23 = K##t##_2 > K##t##_3 ? K##t##_2 : K##t##_3; \
    int m45 = K##t##_4 > K##t##_5 ? K##t##_4 : K##t##_5; \
    int m67 = K##t##_6 > K##t##_7 ? K##t##_6 : K##t##_7; \
    int ma = m01 > m23 ? m01 : m23; int mb = m45 > m67 ? m45 : m67; \
    int mc = ma > mb ? ma : mb; mxK = mxK > mc ? mxK : mc; }
  C4(MXK)
#undef MXK
  mxK = dppmax16i(mxK);

  int lo = -1, hi = mxK, th = 0;
  bool fnd = false;
#pragma unroll 1
  for (int it = 0; it < 32; ++it) {
    const int tm = (lo + hi) >> 1;
    int c = (K32 > tm);
#define CK(t) c += (K##t##_0 > tm) + (K##t##_1 > tm) + (K##t##_2 > tm) + (K##t##_3 > tm) \
             + (K##t##_4 > tm) + (K##t##_5 > tm) + (K##t##_6 > tm) + (K##t##_7 > tm);
    C4(CK)
#undef CK
    c = dppadd16(c);
    if (!fnd) {
      if (c == kk)                   { th = tm; fnd = true; }
      else if (tm <= lo || tm >= hi) { th = lo; fnd = true; }
      else if (c > kk)               lo = tm;
      else                           hi = tm;
    }
    if (__all(fnd)) break;
  }
  if (!fnd) th = lo;

  int h = (int)(ym1 & (unsigned)(K32 > th));
#define HT(t) h += (int)((ym0 >> (8*(t)+0)) & 1u) & (int)(K##t##_0 > th); \
  h += (int)((ym0 >> (8*(t)+1)) & 1u) & (int)(K##t##_1 > th); \
  h += (int)((ym0 >> (8*(t)+2)) & 1u) & (int)(K##t##_2 > th); \
  h += (int)((ym0 >> (8*(t)+3)) & 1u) & (int)(K##t##_3 > th); \
  h += (int)((ym0 >> (8*(t)+4)) & 1u) & (int)(K##t##_4 > th); \
  h += (int)((ym0 >> (8*(t)+5)) & 1u) & (int)(K##t##_5 > th); \
  h += (int)((ym0 >> (8*(t)+6)) & 1u) & (int)(K##t##_6 > th); \
  h += (int)((ym0 >> (8*(t)+7)) & 1u) & (int)(K##t##_7 > th);
  C4(HT)
#undef HT
  h = dppadd16(h);

  float scoreloc = 0.f;
  if (cl == 0) {
    const int hv = h < kk ? h : kk;
    scoreloc = (float)hv / (float)kk;
  }

#pragma unroll
  for (int m = 1; m < 64; m <<= 1) {
    lossloc  += __shfl_xor(lossloc, m, 64);
    scoreloc += __shfl_xor(scoreloc, m, 64);
  }
  if (lane == 0) { redL[w] = lossloc; redS[w] = scoreloc; }
  __syncthreads();
  if (tid == 0) {
    float sl = 0.f, ss = 0.f;
#pragma unroll
    for (int i = 0; i < 16; ++i) { sl += redL[i]; ss += redS[i]; }
    atomicAdd(&accum[0], sl);
    atomicAdd(&accum[1], ss);
  }
}

__global__ void wcvt_kernel(const float* __restrict__ W, short* __restrict__ Wbf,
                            float* __restrict__ ws) {
  if (blockIdx.x == 0 && threadIdx.x == 0) { ws[0] = 0.f; ws[1] = 0.f; }
  int idx = (blockIdx.x * 256 + threadIdx.x) * 4;
  int row = idx >> 9;
  bf16x4 v = {0, 0, 0, 0};
  if (row < CC) {
    f32x4 f = *(const f32x4*)(W + idx);
    v[0]=f2bf(f.x); v[1]=f2bf(f.y); v[2]=f2bf(f.z); v[3]=f2bf(f.w);
  }
  *(bf16x4*)(Wbf + idx) = v;
}

__global__ void init_ws_kernel(float* ws) {
  ws[0] = 0.f;
  ws[1] = 0.f;
}

__global__ void finalize_kernel(const float* __restrict__ ws, float* __restrict__ out) {
  out[0] = (float)((double)ws[0] / ((double)BB * (double)CC));
  out[1] = (float)((double)ws[1] / (double)BB);
}

extern "C" void kernel_launch(void* const* d_in, const int* in_sizes, int n_in,
                              void* d_out, int out_size, void* d_ws, size_t ws_size,
                              hipStream_t stream) {
  const float* x  = (const float*)d_in[0];
  const float* y  = (const float*)d_in[1];
  const float* W  = (const float*)d_in[2];
  const float* b  = (const float*)d_in[3];
  const float* pw = (const float*)d_in[4];
  float* out = (float*)d_out;
  float* ws  = (float*)d_ws;
  short* Wbf = (short*)((char*)d_ws + 64);
  unsigned short* zg = (unsigned short*)((char*)d_ws + 64 + (size_t)NCOLP * DD * 2);

  const size_t need_wbf = 64 + (size_t)NCOLP * DD * 2;                  // 589,888
  const size_t need_z   = need_wbf + (size_t)BB * ZGS * 2;              // +34.6 MB

  if (ws_size >= need_z) {
    // split path: GEMM pass + standalone epilogue pass
    hipFuncSetAttribute(reinterpret_cast<const void*>(&gemm_part),
                        hipFuncAttributeMaxDynamicSharedMemorySize, SMEMB);
    wcvt_kernel<<<dim3(NCOLP * DD / 1024), dim3(256), 0, stream>>>(W, Wbf, ws);
    gemm_part<<<dim3(BB / BM), dim3(1024), SMEMB, stream>>>(x, Wbf, b, zg);
    epi_part<<<dim3(BB / 32), dim3(512), 0, stream>>>(zg, y, pw, ws);
  } else if (ws_size >= need_wbf) {
    void (*kp)(const float*, const float*, const float*, const short*,
               const float*, const float*, float*) = fused_mfma_bce_topk<true>;
    hipFuncSetAttribute(reinterpret_cast<const void*>(kp),
                        hipFuncAttributeMaxDynamicSharedMemorySize, SMEMB);
    wcvt_kernel<<<dim3(NCOLP * DD / 1024), dim3(256), 0, stream>>>(W, Wbf, ws);
    fused_mfma_bce_topk<true><<<dim3(BB / BM), dim3(1024), SMEMB, stream>>>(
        x, y, W, Wbf, b, pw, ws);
  } else {
    void (*kp)(const float*, const float*, const float*, const short*,
               const float*, const float*, float*) = fused_mfma_bce_topk<false>;
    hipFuncSetAttribute(reinterpret_cast<const void*>(kp),
                        hipFuncAttributeMaxDynamicSharedMemorySize, SMEMB);
    init_ws_kernel<<<dim3(1), dim3(1), 0, stream>>>(ws);
    fused_mfma_bce_topk<false><<<dim3(BB / BM), dim3(1024), SMEMB, stream>>>(
        x, y, W, Wbf, b, pw, ws);
  }
  finalize_kernel<<<dim3(1), dim3(1), 0, stream>>>(ws, out);
}